// Round 8
// baseline (5071.592 us; speedup 1.0000x reference)
//
#include <hip/hip_runtime.h>
#include <hip/hip_bf16.h>
#include <stdint.h>

#define NN 131072
#define NE 262144
#define DD 300
#define DP 320
#define D2 600
#define D2P 640
#define NL 5
#define BN_EPS 1e-5f

typedef __attribute__((ext_vector_type(8))) _Float16 f16x8;
typedef __attribute__((ext_vector_type(4))) float f32x4;
typedef __attribute__((ext_vector_type(4))) unsigned int uint4v;
typedef __attribute__((ext_vector_type(4))) short s16x4;

static __device__ __forceinline__ float h2f(unsigned short u) {
    union { unsigned short u; _Float16 h; } c; c.u = u; return (float)c.h;
}
static __device__ __forceinline__ unsigned short f2h(float f) {
    union { unsigned short u; _Float16 h; } c; c.h = (_Float16)f; return c.u;
}

// ---------------- prep kernels ----------------

__global__ void k_w1t(const float* __restrict__ W1, unsigned short* __restrict__ W1t) {
    int idx = blockIdx.x * 256 + threadIdx.x;
    if (idx >= NL * D2P * DP) return;
    int l = idx / (D2P * DP);
    int r = idx % (D2P * DP);
    int n = r / DP, k = r % DP;
    float v = (n < D2 && k < DD) ? W1[(size_t)(l * DD + k) * D2 + n] : 0.f;
    W1t[idx] = f2h(v);
}

__global__ void k_w2t(const float* __restrict__ W2, unsigned short* __restrict__ W2t) {
    int idx = blockIdx.x * 256 + threadIdx.x;
    if (idx >= NL * DP * D2P) return;
    int l = idx / (DP * D2P);
    int r = idx % (DP * D2P);
    int n = r / D2P, k = r % D2P;
    float v = (n < DD && k < D2) ? W2[(size_t)(l * D2 + k) * DD + n] : 0.f;
    W2t[idx] = f2h(v);
}

__global__ void k_eec(const float* __restrict__ ee1, const float* __restrict__ ee2,
                      unsigned short* __restrict__ eec) {
    int idx = blockIdx.x * 256 + threadIdx.x;
    if (idx >= NL * 15 * DP) return;
    int l = idx / (15 * DP);
    int r = idx % (15 * DP);
    int cb = r / DP, c = r % DP;
    int b = cb / 3, d = cb % 3;
    float v = 0.f;
    if (c < DD) v = ee1[(size_t)(l * 5 + b) * DD + c] + ee2[(size_t)(l * 3 + d) * DD + c];
    eec[idx] = f2h(v);
}

__global__ void k_h0(const int* __restrict__ x, const float* __restrict__ xe1,
                     const float* __restrict__ xe2, unsigned short* __restrict__ h) {
    unsigned int idx = blockIdx.x * 256u + threadIdx.x;
    if (idx >= (unsigned int)NN * DP) return;
    unsigned int n = idx / DP, c = idx % DP;
    float v = 0.f;
    if (c < DD) v = xe1[(size_t)x[2 * n] * DD + c] + xe2[(size_t)x[2 * n + 1] * DD + c];
    h[idx] = f2h(v);
}

__global__ void k_ident(float* __restrict__ sc, float* __restrict__ sh) {
    int t = blockIdx.x * 256 + threadIdx.x;
    if (t < DP) { sc[t] = 1.f; sh[t] = 0.f; }
}

// ---------------- CSR build ----------------

__global__ void k_count(const int* __restrict__ ei, int* __restrict__ counts) {
    int e = blockIdx.x * 256 + threadIdx.x;
    if (e < NE) atomicAdd(&counts[ei[NE + e]], 1);
}

__global__ void k_scan1(const int* __restrict__ counts, int* __restrict__ partial) {
    __shared__ int sm[256];
    int t = threadIdx.x;
    sm[t] = counts[blockIdx.x * 256 + t];
    __syncthreads();
    for (int o = 128; o > 0; o >>= 1) {
        if (t < o) sm[t] += sm[t + o];
        __syncthreads();
    }
    if (t == 0) partial[blockIdx.x] = sm[0];
}

__global__ void k_scan2(const int* __restrict__ partial, int* __restrict__ partial2) {
    __shared__ int sm[512];
    int t = threadIdx.x;
    int v = partial[t];
    sm[t] = v;
    __syncthreads();
    for (int o = 1; o < 512; o <<= 1) {
        int add = (t >= o) ? sm[t - o] : 0;
        __syncthreads();
        sm[t] += add;
        __syncthreads();
    }
    partial2[t] = sm[t] - v;  // exclusive
}

__global__ void k_scan3(const int* __restrict__ counts, const int* __restrict__ partial2,
                        int* __restrict__ row_ptr, int* __restrict__ cursor) {
    __shared__ int sm[256];
    int t = threadIdx.x;
    int i = blockIdx.x * 256 + t;
    int v = counts[i];
    sm[t] = v;
    __syncthreads();
    for (int o = 1; o < 256; o <<= 1) {
        int add = (t >= o) ? sm[t - o] : 0;
        __syncthreads();
        sm[t] += add;
        __syncthreads();
    }
    int excl = partial2[blockIdx.x] + sm[t] - v;
    row_ptr[i] = excl;
    cursor[i] = excl;
    if (i == NN - 1) row_ptr[NN] = excl + v;
}

__global__ void k_fill(const int* __restrict__ ei, const int* __restrict__ ea,
                       int* __restrict__ cursor, int* __restrict__ srcs,
                       int* __restrict__ combos) {
    int e = blockIdx.x * 256 + threadIdx.x;
    if (e >= NE) return;
    int d = ei[NE + e];
    int pos = atomicAdd(&cursor[d], 1);
    srcs[pos] = ei[e];
    combos[pos] = ea[2 * e] * 3 + ea[2 * e + 1];
}

// ---------------- aggregation (pull, CSR) ----------------
__global__ void k_gather(const unsigned short* __restrict__ h, const float* __restrict__ sc,
                         const float* __restrict__ sh, int relu,
                         const int* __restrict__ row_ptr, const int* __restrict__ srcs,
                         const int* __restrict__ combos, const unsigned short* __restrict__ eec,
                         unsigned short* __restrict__ agg) {
    unsigned int idx = blockIdx.x * 256u + threadIdx.x;  // N*40 chunks of 8 cols
    if (idx >= (unsigned int)NN * 40) return;
    unsigned int m = idx / 40;
    unsigned int j = idx % 40;
    int c0 = j * 8;
    float a[8] = {0, 0, 0, 0, 0, 0, 0, 0};
    float scv[8], shv[8];
#pragma unroll
    for (int i = 0; i < 8; i++) { scv[i] = sc[c0 + i]; shv[i] = sh[c0 + i]; }
    int e0 = row_ptr[m], e1 = row_ptr[m + 1];
    for (int e = e0; e < e1; ++e) {
        int s = srcs[e], cb = combos[e];
        uint4v hv = *(const uint4v*)(h + (size_t)s * DP + c0);
        uint4v ev = *(const uint4v*)(eec + (size_t)cb * DP + c0);
        const unsigned short* hp = (const unsigned short*)&hv;
        const unsigned short* ep = (const unsigned short*)&ev;
#pragma unroll
        for (int i = 0; i < 8; i++) {
            float f = scv[i] * h2f(hp[i]) + shv[i];
            if (relu) f = fmaxf(f, 0.f);
            a[i] += f + h2f(ep[i]);
        }
    }
    unsigned short o[8];
#pragma unroll
    for (int i = 0; i < 8; i++) o[i] = f2h(a[i]);
    *(uint4v*)(agg + (size_t)m * DP + c0) = *(const uint4v*)o;
}

// ---------------- GEMM: BM=64, BN=320, BK=64; 512 thr = 8 waves (2m x 4n, wave 32x80) ----------------
// Swapped-operand MFMA -> acc holds D^T (lane&15 = m-row, (lane>>4)*4+i = n-col).
// ~50 KB LDS + acc[2][5]=40 VGPR -> 3 blocks/CU target. Counted vmcnt: A(kt+1)
// prefetch stays in flight across the barrier (only 2 sched pins per kt).
#define TLD 328
__launch_bounds__(512, 6)
__global__ void k_gemmN(const unsigned short* __restrict__ A, int lda, int kIters,
                        const unsigned short* __restrict__ scH,
                        const unsigned short* __restrict__ shH,
                        const unsigned short* __restrict__ B,
                        unsigned short* __restrict__ C, int ldc,
                        float* __restrict__ stats, int statN) {
    __shared__ unsigned short smem[64 * 64 + 320 * 64];  // As | Bs ; reused as T[64][TLD]
    __shared__ unsigned short scS[D2P];
    __shared__ unsigned short shS[D2P];
    unsigned short* As = smem;
    unsigned short* Bs = smem + 64 * 64;
    int tid = threadIdx.x;
    int lane = tid & 63, wid = tid >> 6;
    int wm = wid >> 2, wn = wid & 3;     // 2m x 4n
    int m0 = blockIdx.y * 64;
    int n0 = blockIdx.x * 320;
    const unsigned short* Bb = B + (size_t)n0 * lda;

    // A staging: row = tid>>3 (0..63), slot = tid&7 (8 x 16B slots/row)
    int srow = tid >> 3;
    int slot = tid & 7;
    const unsigned short* aRow = A + (size_t)(m0 + srow) * lda + slot * 8;
    int sOff = srow * 64 + ((slot ^ (srow & 7)) * 8);
    // B staging (same as proven round-4 geometry)
    int brow8 = lane >> 3;
    int bc16 = (lane & 7) ^ brow8;

    // stage affine vectors into LDS once
    if (scH) {
        for (int i = tid; i < lda; i += 512) {
            scS[i] = scH[i];
            shS[i] = shH[i];
        }
    }
    __syncthreads();

    f32x4 acc[2][5] = {};
    uint4v vA = *(const uint4v*)(aRow);  // prefetch kt=0

    for (int kt = 0; kt < kIters; ++kt) {
        int k0 = kt * 64;
        // B DMA: 5 chunks/wave, 40 chunks = 320 rows x 64 cols
#pragma unroll
        for (int j = 0; j < 5; ++j) {
            int chunk = wid * 5 + j;
            int n = chunk * 8 + brow8;
            const unsigned short* g = Bb + (size_t)n * lda + k0 + bc16 * 8;
            __builtin_amdgcn_global_load_lds(
                (const __attribute__((address_space(1))) unsigned int*)g,
                (__attribute__((address_space(3))) unsigned int*)&Bs[chunk * 512], 16, 0, 0);
        }
        // pin: DMAs issue before the A-prefetch (so vmcnt(1) leaves only the prefetch)
        __builtin_amdgcn_sched_barrier(0);
        uint4v cur = vA;
        if (kt + 1 < kIters) vA = *(const uint4v*)(aRow + (kt + 1) * 64);
        if (scH) {
            f16x8 a0 = *(f16x8*)&cur;
            f16x8 s0 = *(const f16x8*)&scS[k0 + slot * 8];
            f16x8 h0 = *(const f16x8*)&shS[k0 + slot * 8];
#pragma unroll
            for (int i = 0; i < 8; i++) {
                _Float16 t0 = a0[i] * s0[i] + h0[i];
                a0[i] = t0 > (_Float16)0 ? t0 : (_Float16)0;
            }
            cur = *(uint4v*)&a0;
        }
        *(uint4v*)&As[sOff] = cur;
        // counted wait: B-DMAs + ds_write drained, A(kt+1) prefetch stays in flight
        if (kt + 1 < kIters) {
            asm volatile("s_waitcnt vmcnt(1) lgkmcnt(0)" ::: "memory");
        } else {
            asm volatile("s_waitcnt vmcnt(0) lgkmcnt(0)" ::: "memory");
        }
        __builtin_amdgcn_sched_barrier(0);
        __builtin_amdgcn_s_barrier();
        // compute: left entirely to the compiler's scheduler
#pragma unroll
        for (int ks = 0; ks < 2; ++ks) {
            f16x8 af[2];
#pragma unroll
            for (int mf = 0; mf < 2; ++mf) {
                int ra = wm * 32 + mf * 16 + (lane & 15);
                int c16 = (ks * 4 + (lane >> 4)) ^ (ra & 7);
                af[mf] = *(const f16x8*)&As[ra * 64 + c16 * 8];
            }
#pragma unroll
            for (int nf = 0; nf < 5; ++nf) {
                int rb = wn * 80 + nf * 16 + (lane & 15);
                int c16 = (ks * 4 + (lane >> 4)) ^ (rb & 7);
                f16x8 bg = *(const f16x8*)&Bs[rb * 64 + c16 * 8];
#pragma unroll
                for (int mf = 0; mf < 2; ++mf)
                    acc[mf][nf] = __builtin_amdgcn_mfma_f32_16x16x32_f16(bg, af[mf], acc[mf][nf], 0, 0, 0);
            }
        }
        __builtin_amdgcn_s_barrier();   // As/Bs free for next kt
    }

    // ---- per-column stats (f16-rounded, matching stored C) ----
#pragma unroll
    for (int nf = 0; nf < 5; ++nf) {
        float s[4] = {0, 0, 0, 0}, ss[4] = {0, 0, 0, 0};
#pragma unroll
        for (int mf = 0; mf < 2; ++mf) {
#pragma unroll
            for (int i = 0; i < 4; ++i) {
                float vr = h2f(f2h(acc[mf][nf][i]));
                s[i] += vr;
                ss[i] += vr * vr;
            }
        }
#pragma unroll
        for (int off = 1; off < 16; off <<= 1) {
#pragma unroll
            for (int i = 0; i < 4; ++i) {
                s[i] += __shfl_xor(s[i], off);
                ss[i] += __shfl_xor(ss[i], off);
            }
        }
        if ((lane & 15) == 0) {
            int cb = n0 + wn * 80 + nf * 16 + ((lane >> 4) << 2);
#pragma unroll
            for (int i = 0; i < 4; ++i) {
                atomicAdd(&stats[cb + i], s[i]);
                atomicAdd(&stats[statN + cb + i], ss[i]);
            }
        }
    }

    // ---- single-pass LDS-transpose epilogue ----
    unsigned short* T = smem;  // 64 x TLD f16 = 42 KB (fits in As|Bs region)
#pragma unroll
    for (int nf = 0; nf < 5; ++nf) {
#pragma unroll
        for (int mf = 0; mf < 2; ++mf) {
            int r = wm * 32 + mf * 16 + (lane & 15);
            int cb = wn * 80 + nf * 16 + ((lane >> 4) << 2);
            s16x4 w;
#pragma unroll
            for (int i = 0; i < 4; ++i) w[i] = (short)f2h(acc[mf][nf][i]);
            *(s16x4*)&T[r * TLD + cb] = w;
        }
    }
    __syncthreads();
#pragma unroll
    for (int p = 0; p < 5; ++p) {
        int cid = p * 512 + tid;          // 0..2559 = 64 rows x 40 slots
        int r = cid / 40, c16 = cid % 40;
        uint4v v = *(const uint4v*)&T[r * TLD + c16 * 8];
        *(uint4v*)&C[(size_t)(m0 + r) * ldc + n0 + c16 * 8] = v;
    }
}

// ---------------- BN scale/shift from stats (f32 + f16 copies) ----------------
__global__ void k_bnprep(const float* __restrict__ stats, int statN, int realN,
                         const float* __restrict__ g, const float* __restrict__ b,
                         float* __restrict__ sc, float* __restrict__ sh,
                         unsigned short* __restrict__ scH, unsigned short* __restrict__ shH) {
    int n = blockIdx.x * 256 + threadIdx.x;
    if (n >= statN) return;
    float scv = 0.f, shv = 0.f;
    if (n < realN) {
        float mu = stats[n] * (1.f / NN);
        float var = stats[statN + n] * (1.f / NN) - mu * mu;
        var = fmaxf(var, 0.f);
        float rs = rsqrtf(var + BN_EPS);
        scv = g[n] * rs;
        shv = b[n] - mu * scv;
    }
    sc[n] = scv;
    sh[n] = shv;
    scH[n] = f2h(scv);
    shH[n] = f2h(shv);
}

// ---------------- final output ----------------
__global__ void k_out(const unsigned short* __restrict__ u2, const float* __restrict__ sc,
                      const float* __restrict__ sh, float* __restrict__ out) {
    unsigned int idx = blockIdx.x * 256u + threadIdx.x;
    if (idx >= (unsigned int)NN * DD) return;
    unsigned int n = idx / DD, d = idx % DD;
    out[idx] = sc[d] * h2f(u2[(size_t)n * DP + d]) + sh[d];
}

extern "C" void kernel_launch(void* const* d_in, const int* in_sizes, int n_in,
                              void* d_out, int out_size, void* d_ws, size_t ws_size,
                              hipStream_t stream) {
    const int* x = (const int*)d_in[0];
    const int* ei = (const int*)d_in[1];
    const int* ea = (const int*)d_in[2];
    const float* xe1 = (const float*)d_in[3];
    const float* xe2 = (const float*)d_in[4];
    const float* ee1 = (const float*)d_in[5];
    const float* ee2 = (const float*)d_in[6];
    const float* W1 = (const float*)d_in[7];
    const float* bn1g = (const float*)d_in[9];
    const float* bn1b = (const float*)d_in[10];
    const float* W2 = (const float*)d_in[11];
    const float* bng = (const float*)d_in[13];
    const float* bnb = (const float*)d_in[14];
    float* out = (float*)d_out;

    char* ws = (char*)d_ws;
    size_t off = 0;
    auto alloc = [&](size_t bytes) -> void* {
        void* p = ws + off;
        off += (bytes + 255) & ~(size_t)255;
        return p;
    };
    unsigned short* hbuf = (unsigned short*)alloc((size_t)NN * DP * 2);   // h0 / u2
    unsigned short* agg  = (unsigned short*)alloc((size_t)NN * DP * 2);
    unsigned short* u1   = (unsigned short*)alloc((size_t)NN * D2P * 2);
    unsigned short* W1t  = (unsigned short*)alloc((size_t)NL * D2P * DP * 2);
    unsigned short* W2t  = (unsigned short*)alloc((size_t)NL * DP * D2P * 2);
    unsigned short* eec  = (unsigned short*)alloc((size_t)NL * 15 * DP * 2);
    int* row_ptr = (int*)alloc((size_t)(NN + 1) * 4);
    int* cursor  = (int*)alloc((size_t)NN * 4);
    int* counts  = (int*)alloc((size_t)NN * 4);
    int* srcs    = (int*)alloc((size_t)NE * 4);
    int* combos  = (int*)alloc((size_t)NE * 4);
    int* partial  = (int*)alloc(512 * 4);
    int* partial2 = (int*)alloc(512 * 4);
    float* stats1 = (float*)alloc(2 * D2P * 4);
    float* stats2 = (float*)alloc(2 * DP * 4);
    float* sc1 = (float*)alloc(D2P * 4);
    float* sh1 = (float*)alloc(D2P * 4);
    float* sc2 = (float*)alloc(DP * 4);
    float* sh2 = (float*)alloc(DP * 4);
    float* sc0 = (float*)alloc(DP * 4);
    float* sh0 = (float*)alloc(DP * 4);
    unsigned short* scH1 = (unsigned short*)alloc(D2P * 2);
    unsigned short* shH1 = (unsigned short*)alloc(D2P * 2);
    unsigned short* scH2 = (unsigned short*)alloc(DP * 2);
    unsigned short* shH2 = (unsigned short*)alloc(DP * 2);

    // prep
    k_w1t<<<NL * D2P * DP / 256, 256, 0, stream>>>(W1, W1t);
    k_w2t<<<NL * DP * D2P / 256, 256, 0, stream>>>(W2, W2t);
    k_eec<<<(NL * 15 * DP + 255) / 256, 256, 0, stream>>>(ee1, ee2, eec);
    k_h0<<<NN * DP / 256, 256, 0, stream>>>(x, xe1, xe2, hbuf);
    k_ident<<<2, 256, 0, stream>>>(sc0, sh0);

    // CSR
    hipMemsetAsync(counts, 0, (size_t)NN * 4, stream);
    k_count<<<NE / 256, 256, 0, stream>>>(ei, counts);
    k_scan1<<<NN / 256, 256, 0, stream>>>(counts, partial);
    k_scan2<<<1, 512, 0, stream>>>(partial, partial2);
    k_scan3<<<NN / 256, 256, 0, stream>>>(counts, partial2, row_ptr, cursor);
    k_fill<<<NE / 256, 256, 0, stream>>>(ei, ea, cursor, srcs, combos);

    const unsigned short* hcur = hbuf;
    const float* scIn = sc0;
    const float* shIn = sh0;
    int reluIn = 0;
    for (int l = 0; l < NL; ++l) {
        k_gather<<<NN * 40 / 256, 256, 0, stream>>>(hcur, scIn, shIn, reluIn, row_ptr, srcs,
                                                    combos, eec + (size_t)l * 15 * DP, agg);
        hipMemsetAsync(stats1, 0, 2 * D2P * 4, stream);
        dim3 g1(D2P / 320, NN / 64);
        k_gemmN<<<g1, 512, 0, stream>>>(agg, DP, DP / 64, nullptr, nullptr,
                                        W1t + (size_t)l * D2P * DP, u1, D2P, stats1, D2P);
        k_bnprep<<<(D2P + 255) / 256, 256, 0, stream>>>(stats1, D2P, D2, bn1g + (size_t)l * D2,
                                                        bn1b + (size_t)l * D2, sc1, sh1, scH1, shH1);
        hipMemsetAsync(stats2, 0, 2 * DP * 4, stream);
        dim3 g2(DP / 320, NN / 64);
        k_gemmN<<<g2, 512, 0, stream>>>(u1, D2P, D2P / 64, scH1, shH1,
                                        W2t + (size_t)l * DP * D2P, hbuf, DP, stats2, DP);
        k_bnprep<<<(DP + 255) / 256, 256, 0, stream>>>(stats2, DP, DD, bng + (size_t)l * DD,
                                                       bnb + (size_t)l * DD, sc2, sh2, scH2, shH2);
        hcur = hbuf;
        scIn = sc2;
        shIn = sh2;
        reluIn = 1;
    }
    k_out<<<(unsigned int)NN * DD / 256, 256, 0, stream>>>(hbuf, sc2, sh2, out);
}

// Round 9
// 4685.471 us; speedup vs baseline: 1.0824x; 1.0824x over previous
//
#include <hip/hip_runtime.h>
#include <hip/hip_bf16.h>
#include <stdint.h>

#define NN 131072
#define NE 262144
#define DD 300
#define DP 320
#define D2 600
#define D2P 640
#define NL 5
#define BN_EPS 1e-5f

typedef __attribute__((ext_vector_type(8))) _Float16 f16x8;
typedef __attribute__((ext_vector_type(4))) float f32x4;
typedef __attribute__((ext_vector_type(4))) unsigned int uint4v;
typedef __attribute__((ext_vector_type(4))) short s16x4;

static __device__ __forceinline__ float h2f(unsigned short u) {
    union { unsigned short u; _Float16 h; } c; c.u = u; return (float)c.h;
}
static __device__ __forceinline__ unsigned short f2h(float f) {
    union { unsigned short u; _Float16 h; } c; c.h = (_Float16)f; return c.u;
}

// ---------------- prep kernels ----------------

__global__ void k_w1t(const float* __restrict__ W1, unsigned short* __restrict__ W1t) {
    int idx = blockIdx.x * 256 + threadIdx.x;
    if (idx >= NL * D2P * DP) return;
    int l = idx / (D2P * DP);
    int r = idx % (D2P * DP);
    int n = r / DP, k = r % DP;
    float v = (n < D2 && k < DD) ? W1[(size_t)(l * DD + k) * D2 + n] : 0.f;
    W1t[idx] = f2h(v);
}

__global__ void k_w2t(const float* __restrict__ W2, unsigned short* __restrict__ W2t) {
    int idx = blockIdx.x * 256 + threadIdx.x;
    if (idx >= NL * DP * D2P) return;
    int l = idx / (DP * D2P);
    int r = idx % (DP * D2P);
    int n = r / D2P, k = r % D2P;
    float v = (n < DD && k < D2) ? W2[(size_t)(l * D2 + k) * DD + n] : 0.f;
    W2t[idx] = f2h(v);
}

__global__ void k_eec(const float* __restrict__ ee1, const float* __restrict__ ee2,
                      unsigned short* __restrict__ eec) {
    int idx = blockIdx.x * 256 + threadIdx.x;
    if (idx >= NL * 15 * DP) return;
    int l = idx / (15 * DP);
    int r = idx % (15 * DP);
    int cb = r / DP, c = r % DP;
    int b = cb / 3, d = cb % 3;
    float v = 0.f;
    if (c < DD) v = ee1[(size_t)(l * 5 + b) * DD + c] + ee2[(size_t)(l * 3 + d) * DD + c];
    eec[idx] = f2h(v);
}

__global__ void k_h0(const int* __restrict__ x, const float* __restrict__ xe1,
                     const float* __restrict__ xe2, unsigned short* __restrict__ h) {
    unsigned int idx = blockIdx.x * 256u + threadIdx.x;
    if (idx >= (unsigned int)NN * DP) return;
    unsigned int n = idx / DP, c = idx % DP;
    float v = 0.f;
    if (c < DD) v = xe1[(size_t)x[2 * n] * DD + c] + xe2[(size_t)x[2 * n + 1] * DD + c];
    h[idx] = f2h(v);
}

__global__ void k_ident(float* __restrict__ sc, float* __restrict__ sh) {
    int t = blockIdx.x * 256 + threadIdx.x;
    if (t < DP) { sc[t] = 1.f; sh[t] = 0.f; }
}

// ---------------- CSR build ----------------

__global__ void k_count(const int* __restrict__ ei, int* __restrict__ counts) {
    int e = blockIdx.x * 256 + threadIdx.x;
    if (e < NE) atomicAdd(&counts[ei[NE + e]], 1);
}

__global__ void k_scan1(const int* __restrict__ counts, int* __restrict__ partial) {
    __shared__ int sm[256];
    int t = threadIdx.x;
    sm[t] = counts[blockIdx.x * 256 + t];
    __syncthreads();
    for (int o = 128; o > 0; o >>= 1) {
        if (t < o) sm[t] += sm[t + o];
        __syncthreads();
    }
    if (t == 0) partial[blockIdx.x] = sm[0];
}

__global__ void k_scan2(const int* __restrict__ partial, int* __restrict__ partial2) {
    __shared__ int sm[512];
    int t = threadIdx.x;
    int v = partial[t];
    sm[t] = v;
    __syncthreads();
    for (int o = 1; o < 512; o <<= 1) {
        int add = (t >= o) ? sm[t - o] : 0;
        __syncthreads();
        sm[t] += add;
        __syncthreads();
    }
    partial2[t] = sm[t] - v;  // exclusive
}

__global__ void k_scan3(const int* __restrict__ counts, const int* __restrict__ partial2,
                        int* __restrict__ row_ptr, int* __restrict__ cursor) {
    __shared__ int sm[256];
    int t = threadIdx.x;
    int i = blockIdx.x * 256 + t;
    int v = counts[i];
    sm[t] = v;
    __syncthreads();
    for (int o = 1; o < 256; o <<= 1) {
        int add = (t >= o) ? sm[t - o] : 0;
        __syncthreads();
        sm[t] += add;
        __syncthreads();
    }
    int excl = partial2[blockIdx.x] + sm[t] - v;
    row_ptr[i] = excl;
    cursor[i] = excl;
    if (i == NN - 1) row_ptr[NN] = excl + v;
}

__global__ void k_fill(const int* __restrict__ ei, const int* __restrict__ ea,
                       int* __restrict__ cursor, int* __restrict__ srcs,
                       int* __restrict__ combos) {
    int e = blockIdx.x * 256 + threadIdx.x;
    if (e >= NE) return;
    int d = ei[NE + e];
    int pos = atomicAdd(&cursor[d], 1);
    srcs[pos] = ei[e];
    combos[pos] = ea[2 * e] * 3 + ea[2 * e + 1];
}

// ---------------- aggregation (pull, CSR) ----------------
__global__ void k_gather(const unsigned short* __restrict__ h, const float* __restrict__ sc,
                         const float* __restrict__ sh, int relu,
                         const int* __restrict__ row_ptr, const int* __restrict__ srcs,
                         const int* __restrict__ combos, const unsigned short* __restrict__ eec,
                         unsigned short* __restrict__ agg) {
    unsigned int idx = blockIdx.x * 256u + threadIdx.x;  // N*40 chunks of 8 cols
    if (idx >= (unsigned int)NN * 40) return;
    unsigned int m = idx / 40;
    unsigned int j = idx % 40;
    int c0 = j * 8;
    float a[8] = {0, 0, 0, 0, 0, 0, 0, 0};
    float scv[8], shv[8];
#pragma unroll
    for (int i = 0; i < 8; i++) { scv[i] = sc[c0 + i]; shv[i] = sh[c0 + i]; }
    int e0 = row_ptr[m], e1 = row_ptr[m + 1];
    for (int e = e0; e < e1; ++e) {
        int s = srcs[e], cb = combos[e];
        uint4v hv = *(const uint4v*)(h + (size_t)s * DP + c0);
        uint4v ev = *(const uint4v*)(eec + (size_t)cb * DP + c0);
        const unsigned short* hp = (const unsigned short*)&hv;
        const unsigned short* ep = (const unsigned short*)&ev;
#pragma unroll
        for (int i = 0; i < 8; i++) {
            float f = scv[i] * h2f(hp[i]) + shv[i];
            if (relu) f = fmaxf(f, 0.f);
            a[i] += f + h2f(ep[i]);
        }
    }
    unsigned short o[8];
#pragma unroll
    for (int i = 0; i < 8; i++) o[i] = f2h(a[i]);
    *(uint4v*)(agg + (size_t)m * DP + c0) = *(const uint4v*)o;
}

// ---------------- A-stationary streaming GEMM ----------------
// C[64 rows x NW*80 cols] = affine?(A) @ B^T.  BM=64, full N per block.
// A half-tile [64][320] staged ONCE per K-half into swizzled LDS; B streamed
// per-fragment from global (L2-resident, ~0.4-0.8 MB). NO barriers in the
// K-loop -> no barrier-quantum stalls; waves run free, ILP+TLP hide latency.
// Swapped-operand MFMA: acc frag = (lane&15 -> m-row, (lane>>4)*4+i -> n-col).
// NW = n-split waves (8 or 4), MFRAG = m-frags per wave, KH = K halves.
#define TLD 328
template<int NW, int MFRAG, int KH>
__launch_bounds__(512, 2)
__global__ void k_gemmS(const unsigned short* __restrict__ A, int lda,
                        const unsigned short* __restrict__ scH,
                        const unsigned short* __restrict__ shH,
                        const unsigned short* __restrict__ B, int ldb,
                        unsigned short* __restrict__ C, int ldc,
                        float* __restrict__ stats, int statN) {
    __shared__ unsigned short smem[64 * TLD];  // A-tile [64][320] ; reused as T[64][TLD]
    unsigned short* As = smem;
    int tid = threadIdx.x;
    int lane = tid & 63, wid = tid >> 6;
    int wn = wid % NW, wm = wid / NW;
    int l15 = lane & 15, l4 = lane >> 4;
    int m0 = blockIdx.x * 64;

    f32x4 acc[MFRAG][5] = {};

    for (int kh = 0; kh < KH; ++kh) {
        if (kh) __syncthreads();   // all waves done reading As before restage
        // ---- stage A half [64][320] -> swizzled LDS (affine+relu folded) ----
#pragma unroll
        for (int p = 0; p < 5; ++p) {
            int id = p * 512 + tid;            // 2560 chunks = 64 rows x 40
            int row = id / 40, c = id % 40;
            const unsigned short* g = A + (size_t)(m0 + row) * lda + kh * 320 + c * 8;
            uint4v v = *(const uint4v*)g;
            if (scH) {
                f16x8 a = *(f16x8*)&v;
                f16x8 s = *(const f16x8*)&scH[kh * 320 + c * 8];
                f16x8 h = *(const f16x8*)&shH[kh * 320 + c * 8];
#pragma unroll
                for (int i = 0; i < 8; ++i) {
                    _Float16 t = a[i] * s[i] + h[i];
                    a[i] = t > (_Float16)0 ? t : (_Float16)0;
                }
                v = *(uint4v*)&a;
            }
            *(uint4v*)&As[row * 320 + ((c ^ (row & 7)) * 8)] = v;
        }
        __syncthreads();
        // ---- barrier-free K x N loop ----
        const unsigned short* Bp = B + (size_t)(wn * 80 + l15) * ldb + kh * 320 + l4 * 8;
#pragma unroll 2
        for (int kt = 0; kt < 10; ++kt) {
            f16x8 af[MFRAG];
            int cc = kt * 4 + l4;
#pragma unroll
            for (int mf = 0; mf < MFRAG; ++mf) {
                int row = (wm * MFRAG + mf) * 16 + l15;
                af[mf] = *(const f16x8*)&As[row * 320 + ((cc ^ (row & 7)) * 8)];
            }
#pragma unroll
            for (int nf = 0; nf < 5; ++nf) {
                f16x8 bg = *(const f16x8*)(Bp + (size_t)nf * 16 * ldb + kt * 32);
#pragma unroll
                for (int mf = 0; mf < MFRAG; ++mf)
                    acc[mf][nf] = __builtin_amdgcn_mfma_f32_16x16x32_f16(bg, af[mf], acc[mf][nf], 0, 0, 0);
            }
        }
    }

    // ---- per-column stats (f16-rounded, matching stored C) ----
#pragma unroll
    for (int nf = 0; nf < 5; ++nf) {
        float s[4] = {0, 0, 0, 0}, ss[4] = {0, 0, 0, 0};
#pragma unroll
        for (int mf = 0; mf < MFRAG; ++mf) {
#pragma unroll
            for (int i = 0; i < 4; ++i) {
                float vr = h2f(f2h(acc[mf][nf][i]));
                s[i] += vr;
                ss[i] += vr * vr;
            }
        }
#pragma unroll
        for (int off = 1; off < 16; off <<= 1) {
#pragma unroll
            for (int i = 0; i < 4; ++i) {
                s[i] += __shfl_xor(s[i], off);
                ss[i] += __shfl_xor(ss[i], off);
            }
        }
        if (l15 == 0) {
            int cb = wn * 80 + nf * 16 + l4 * 4;
#pragma unroll
            for (int i = 0; i < 4; ++i) {
                atomicAdd(&stats[cb + i], s[i]);
                atomicAdd(&stats[statN + cb + i], ss[i]);
            }
        }
    }

    // ---- LDS-transpose epilogue: b64 writes, coalesced dwordx4 row stores ----
    unsigned short* T = smem;
    constexpr int NPASS = NW / 4;   // 2 passes for NW=8 (640 cols), 1 for NW=4
#pragma unroll
    for (int p = 0; p < NPASS; ++p) {
        __syncthreads();
        if ((wn >> 2) == p) {
#pragma unroll
            for (int nf = 0; nf < 5; ++nf) {
#pragma unroll
                for (int mf = 0; mf < MFRAG; ++mf) {
                    int r = (wm * MFRAG + mf) * 16 + l15;
                    int cb = (wn & 3) * 80 + nf * 16 + l4 * 4;
                    s16x4 w;
#pragma unroll
                    for (int i = 0; i < 4; ++i) w[i] = (short)f2h(acc[mf][nf][i]);
                    *(s16x4*)&T[r * TLD + cb] = w;
                }
            }
        }
        __syncthreads();
#pragma unroll
        for (int q = 0; q < 5; ++q) {
            int cid = q * 512 + tid;          // 0..2559 = 64 rows x 40 slots
            int r = cid / 40, c = cid % 40;
            uint4v v = *(const uint4v*)&T[r * TLD + c * 8];
            *(uint4v*)&C[(size_t)(m0 + r) * ldc + p * 320 + c * 8] = v;
        }
    }
}

// ---------------- BN scale/shift from stats (f32 + f16 copies) ----------------
__global__ void k_bnprep(const float* __restrict__ stats, int statN, int realN,
                         const float* __restrict__ g, const float* __restrict__ b,
                         float* __restrict__ sc, float* __restrict__ sh,
                         unsigned short* __restrict__ scH, unsigned short* __restrict__ shH) {
    int n = blockIdx.x * 256 + threadIdx.x;
    if (n >= statN) return;
    float scv = 0.f, shv = 0.f;
    if (n < realN) {
        float mu = stats[n] * (1.f / NN);
        float var = stats[statN + n] * (1.f / NN) - mu * mu;
        var = fmaxf(var, 0.f);
        float rs = rsqrtf(var + BN_EPS);
        scv = g[n] * rs;
        shv = b[n] - mu * scv;
    }
    sc[n] = scv;
    sh[n] = shv;
    scH[n] = f2h(scv);
    shH[n] = f2h(shv);
}

// ---------------- final output ----------------
__global__ void k_out(const unsigned short* __restrict__ u2, const float* __restrict__ sc,
                      const float* __restrict__ sh, float* __restrict__ out) {
    unsigned int idx = blockIdx.x * 256u + threadIdx.x;
    if (idx >= (unsigned int)NN * DD) return;
    unsigned int n = idx / DD, d = idx % DD;
    out[idx] = sc[d] * h2f(u2[(size_t)n * DP + d]) + sh[d];
}

extern "C" void kernel_launch(void* const* d_in, const int* in_sizes, int n_in,
                              void* d_out, int out_size, void* d_ws, size_t ws_size,
                              hipStream_t stream) {
    const int* x = (const int*)d_in[0];
    const int* ei = (const int*)d_in[1];
    const int* ea = (const int*)d_in[2];
    const float* xe1 = (const float*)d_in[3];
    const float* xe2 = (const float*)d_in[4];
    const float* ee1 = (const float*)d_in[5];
    const float* ee2 = (const float*)d_in[6];
    const float* W1 = (const float*)d_in[7];
    const float* bn1g = (const float*)d_in[9];
    const float* bn1b = (const float*)d_in[10];
    const float* W2 = (const float*)d_in[11];
    const float* bng = (const float*)d_in[13];
    const float* bnb = (const float*)d_in[14];
    float* out = (float*)d_out;

    char* ws = (char*)d_ws;
    size_t off = 0;
    auto alloc = [&](size_t bytes) -> void* {
        void* p = ws + off;
        off += (bytes + 255) & ~(size_t)255;
        return p;
    };
    unsigned short* hbuf = (unsigned short*)alloc((size_t)NN * DP * 2);   // h0 / u2
    unsigned short* agg  = (unsigned short*)alloc((size_t)NN * DP * 2);
    unsigned short* u1   = (unsigned short*)alloc((size_t)NN * D2P * 2);
    unsigned short* W1t  = (unsigned short*)alloc((size_t)NL * D2P * DP * 2);
    unsigned short* W2t  = (unsigned short*)alloc((size_t)NL * DP * D2P * 2);
    unsigned short* eec  = (unsigned short*)alloc((size_t)NL * 15 * DP * 2);
    int* row_ptr = (int*)alloc((size_t)(NN + 1) * 4);
    int* cursor  = (int*)alloc((size_t)NN * 4);
    int* counts  = (int*)alloc((size_t)NN * 4);
    int* srcs    = (int*)alloc((size_t)NE * 4);
    int* combos  = (int*)alloc((size_t)NE * 4);
    int* partial  = (int*)alloc(512 * 4);
    int* partial2 = (int*)alloc(512 * 4);
    float* stats1 = (float*)alloc(2 * D2P * 4);
    float* stats2 = (float*)alloc(2 * DP * 4);
    float* sc1 = (float*)alloc(D2P * 4);
    float* sh1 = (float*)alloc(D2P * 4);
    float* sc2 = (float*)alloc(DP * 4);
    float* sh2 = (float*)alloc(DP * 4);
    float* sc0 = (float*)alloc(DP * 4);
    float* sh0 = (float*)alloc(DP * 4);
    unsigned short* scH1 = (unsigned short*)alloc(D2P * 2);
    unsigned short* shH1 = (unsigned short*)alloc(D2P * 2);
    unsigned short* scH2 = (unsigned short*)alloc(DP * 2);
    unsigned short* shH2 = (unsigned short*)alloc(DP * 2);

    // prep
    k_w1t<<<NL * D2P * DP / 256, 256, 0, stream>>>(W1, W1t);
    k_w2t<<<NL * DP * D2P / 256, 256, 0, stream>>>(W2, W2t);
    k_eec<<<(NL * 15 * DP + 255) / 256, 256, 0, stream>>>(ee1, ee2, eec);
    k_h0<<<NN * DP / 256, 256, 0, stream>>>(x, xe1, xe2, hbuf);
    k_ident<<<2, 256, 0, stream>>>(sc0, sh0);

    // CSR
    hipMemsetAsync(counts, 0, (size_t)NN * 4, stream);
    k_count<<<NE / 256, 256, 0, stream>>>(ei, counts);
    k_scan1<<<NN / 256, 256, 0, stream>>>(counts, partial);
    k_scan2<<<1, 512, 0, stream>>>(partial, partial2);
    k_scan3<<<NN / 256, 256, 0, stream>>>(counts, partial2, row_ptr, cursor);
    k_fill<<<NE / 256, 256, 0, stream>>>(ei, ea, cursor, srcs, combos);

    const unsigned short* hcur = hbuf;
    const float* scIn = sc0;
    const float* shIn = sh0;
    int reluIn = 0;
    for (int l = 0; l < NL; ++l) {
        k_gather<<<NN * 40 / 256, 256, 0, stream>>>(hcur, scIn, shIn, reluIn, row_ptr, srcs,
                                                    combos, eec + (size_t)l * 15 * DP, agg);
        hipMemsetAsync(stats1, 0, 2 * D2P * 4, stream);
        // GEMM1: [N,320] @ W1t^T -> [N,640]; NW=8, MFRAG=4, KH=1
        k_gemmS<8, 4, 1><<<NN / 64, 512, 0, stream>>>(agg, DP, nullptr, nullptr,
                                                      W1t + (size_t)l * D2P * DP, DP,
                                                      u1, D2P, stats1, D2P);
        k_bnprep<<<(D2P + 255) / 256, 256, 0, stream>>>(stats1, D2P, D2, bn1g + (size_t)l * D2,
                                                        bn1b + (size_t)l * D2, sc1, sh1, scH1, shH1);
        hipMemsetAsync(stats2, 0, 2 * DP * 4, stream);
        // GEMM2: [N,640] @ W2t^T -> [N,320]; NW=4, MFRAG=2, KH=2; BN1+ReLU folded on A
        k_gemmS<4, 2, 2><<<NN / 64, 512, 0, stream>>>(u1, D2P, scH1, shH1,
                                                      W2t + (size_t)l * DP * D2P, D2P,
                                                      hbuf, DP, stats2, DP);
        k_bnprep<<<(DP + 255) / 256, 256, 0, stream>>>(stats2, DP, DD, bng + (size_t)l * DD,
                                                       bnb + (size_t)l * DD, sc2, sh2, scH2, shH2);
        hcur = hbuf;
        scIn = sc2;
        shIn = sh2;
        reluIn = 1;
    }
    k_out<<<(unsigned int)NN * DD / 256, 256, 0, stream>>>(hbuf, sc2, sh2, out);
}

// Round 10
// 3314.210 us; speedup vs baseline: 1.5303x; 1.4138x over previous
//
#include <hip/hip_runtime.h>
#include <hip/hip_bf16.h>
#include <stdint.h>

#define NN 131072
#define NE 262144
#define DD 300
#define DP 320
#define D2 600
#define D2P 640
#define NL 5
#define BN_EPS 1e-5f

typedef __attribute__((ext_vector_type(8))) _Float16 f16x8;
typedef __attribute__((ext_vector_type(4))) float f32x4;
typedef __attribute__((ext_vector_type(4))) unsigned int uint4v;
typedef __attribute__((ext_vector_type(4))) short s16x4;

static __device__ __forceinline__ float h2f(unsigned short u) {
    union { unsigned short u; _Float16 h; } c; c.u = u; return (float)c.h;
}
static __device__ __forceinline__ unsigned short f2h(float f) {
    union { unsigned short u; _Float16 h; } c; c.h = (_Float16)f; return c.u;
}

// ---------------- prep kernels ----------------

__global__ void k_w1t(const float* __restrict__ W1, unsigned short* __restrict__ W1t) {
    int idx = blockIdx.x * 256 + threadIdx.x;
    if (idx >= NL * D2P * DP) return;
    int l = idx / (D2P * DP);
    int r = idx % (D2P * DP);
    int n = r / DP, k = r % DP;
    float v = (n < D2 && k < DD) ? W1[(size_t)(l * DD + k) * D2 + n] : 0.f;
    W1t[idx] = f2h(v);
}

__global__ void k_w2t(const float* __restrict__ W2, unsigned short* __restrict__ W2t) {
    int idx = blockIdx.x * 256 + threadIdx.x;
    if (idx >= NL * DP * D2P) return;
    int l = idx / (DP * D2P);
    int r = idx % (DP * D2P);
    int n = r / D2P, k = r % D2P;
    float v = (n < DD && k < D2) ? W2[(size_t)(l * D2 + k) * DD + n] : 0.f;
    W2t[idx] = f2h(v);
}

__global__ void k_eec(const float* __restrict__ ee1, const float* __restrict__ ee2,
                      unsigned short* __restrict__ eec) {
    int idx = blockIdx.x * 256 + threadIdx.x;
    if (idx >= NL * 15 * DP) return;
    int l = idx / (15 * DP);
    int r = idx % (15 * DP);
    int cb = r / DP, c = r % DP;
    int b = cb / 3, d = cb % 3;
    float v = 0.f;
    if (c < DD) v = ee1[(size_t)(l * 5 + b) * DD + c] + ee2[(size_t)(l * 3 + d) * DD + c];
    eec[idx] = f2h(v);
}

__global__ void k_h0(const int* __restrict__ x, const float* __restrict__ xe1,
                     const float* __restrict__ xe2, unsigned short* __restrict__ h) {
    unsigned int idx = blockIdx.x * 256u + threadIdx.x;
    if (idx >= (unsigned int)NN * DP) return;
    unsigned int n = idx / DP, c = idx % DP;
    float v = 0.f;
    if (c < DD) v = xe1[(size_t)x[2 * n] * DD + c] + xe2[(size_t)x[2 * n + 1] * DD + c];
    h[idx] = f2h(v);
}

__global__ void k_ident(float* __restrict__ sc, float* __restrict__ sh) {
    int t = blockIdx.x * 256 + threadIdx.x;
    if (t < DP) { sc[t] = 1.f; sh[t] = 0.f; }
}

// ---------------- CSR build ----------------

__global__ void k_count(const int* __restrict__ ei, int* __restrict__ counts) {
    int e = blockIdx.x * 256 + threadIdx.x;
    if (e < NE) atomicAdd(&counts[ei[NE + e]], 1);
}

__global__ void k_scan1(const int* __restrict__ counts, int* __restrict__ partial) {
    __shared__ int sm[256];
    int t = threadIdx.x;
    sm[t] = counts[blockIdx.x * 256 + t];
    __syncthreads();
    for (int o = 128; o > 0; o >>= 1) {
        if (t < o) sm[t] += sm[t + o];
        __syncthreads();
    }
    if (t == 0) partial[blockIdx.x] = sm[0];
}

__global__ void k_scan2(const int* __restrict__ partial, int* __restrict__ partial2) {
    __shared__ int sm[512];
    int t = threadIdx.x;
    int v = partial[t];
    sm[t] = v;
    __syncthreads();
    for (int o = 1; o < 512; o <<= 1) {
        int add = (t >= o) ? sm[t - o] : 0;
        __syncthreads();
        sm[t] += add;
        __syncthreads();
    }
    partial2[t] = sm[t] - v;  // exclusive
}

__global__ void k_scan3(const int* __restrict__ counts, const int* __restrict__ partial2,
                        int* __restrict__ row_ptr, int* __restrict__ cursor) {
    __shared__ int sm[256];
    int t = threadIdx.x;
    int i = blockIdx.x * 256 + t;
    int v = counts[i];
    sm[t] = v;
    __syncthreads();
    for (int o = 1; o < 256; o <<= 1) {
        int add = (t >= o) ? sm[t - o] : 0;
        __syncthreads();
        sm[t] += add;
        __syncthreads();
    }
    int excl = partial2[blockIdx.x] + sm[t] - v;
    row_ptr[i] = excl;
    cursor[i] = excl;
    if (i == NN - 1) row_ptr[NN] = excl + v;
}

__global__ void k_fill(const int* __restrict__ ei, const int* __restrict__ ea,
                       int* __restrict__ cursor, int* __restrict__ srcs,
                       int* __restrict__ combos) {
    int e = blockIdx.x * 256 + threadIdx.x;
    if (e >= NE) return;
    int d = ei[NE + e];
    int pos = atomicAdd(&cursor[d], 1);
    srcs[pos] = ei[e];
    combos[pos] = ea[2 * e] * 3 + ea[2 * e + 1];
}

// ---------------- aggregation (pull, CSR) ----------------
__global__ void k_gather(const unsigned short* __restrict__ h, const float* __restrict__ sc,
                         const float* __restrict__ sh, int relu,
                         const int* __restrict__ row_ptr, const int* __restrict__ srcs,
                         const int* __restrict__ combos, const unsigned short* __restrict__ eec,
                         unsigned short* __restrict__ agg) {
    unsigned int idx = blockIdx.x * 256u + threadIdx.x;  // N*40 chunks of 8 cols
    if (idx >= (unsigned int)NN * 40) return;
    unsigned int m = idx / 40;
    unsigned int j = idx % 40;
    int c0 = j * 8;
    float a[8] = {0, 0, 0, 0, 0, 0, 0, 0};
    float scv[8], shv[8];
#pragma unroll
    for (int i = 0; i < 8; i++) { scv[i] = sc[c0 + i]; shv[i] = sh[c0 + i]; }
    int e0 = row_ptr[m], e1 = row_ptr[m + 1];
    for (int e = e0; e < e1; ++e) {
        int s = srcs[e], cb = combos[e];
        uint4v hv = *(const uint4v*)(h + (size_t)s * DP + c0);
        uint4v ev = *(const uint4v*)(eec + (size_t)cb * DP + c0);
        const unsigned short* hp = (const unsigned short*)&hv;
        const unsigned short* ep = (const unsigned short*)&ev;
#pragma unroll
        for (int i = 0; i < 8; i++) {
            float f = scv[i] * h2f(hp[i]) + shv[i];
            if (relu) f = fmaxf(f, 0.f);
            a[i] += f + h2f(ep[i]);
        }
    }
    unsigned short o[8];
#pragma unroll
    for (int i = 0; i < 8; i++) o[i] = f2h(a[i]);
    *(uint4v*)(agg + (size_t)m * DP + c0) = *(const uint4v*)o;
}

// ---------------- big-N GEMM, round-4 tiling + double-buffered 1-barrier pipeline ----------------
// C[M, n0..n0+319] = affine?(A)[M,K] @ B^T, grid (Nout/320, M/128), 512 thr, 8 waves (2m x 4n).
// Per kt: stage(kt+1) into other buffers -> compute(kt) -> s_waitcnt vmcnt(2) (A(kt+2)
// prefetch stays in flight; B(kt+1) DMA drained AFTER a full compute phase) -> ONE s_barrier.
// Dynamic LDS 114.5 KB: bufA[2][128*64] | bufB[2][320*64] | scS/shS.
#define TLD 328
#define SMEM_SHORTS (2 * 8192 + 2 * 20480 + 2 * D2P)
__launch_bounds__(512)
__global__ void k_gemmN(const unsigned short* __restrict__ A, int lda, int kIters,
                        const unsigned short* __restrict__ scH,
                        const unsigned short* __restrict__ shH,
                        const unsigned short* __restrict__ B,
                        unsigned short* __restrict__ C, int ldc,
                        float* __restrict__ stats, int statN) {
    extern __shared__ unsigned short smem[];
    unsigned short* scS = smem + 57344;
    unsigned short* shS = smem + 57344 + D2P;
    int tid = threadIdx.x;
    int lane = tid & 63, wid = tid >> 6;
    int wm = wid >> 2, wn = wid & 3;
    int m0 = blockIdx.y * 128;
    int n0 = blockIdx.x * 320;
    const unsigned short* Bb = B + (size_t)n0 * lda;

    // A staging geometry: thread -> (row, two 16B slots)
    int srow = tid >> 2;       // 0..127
    int sc16 = tid & 3;        // slots sc16, sc16+4
    int swz = srow & 7;
    const unsigned short* aRow = A + (size_t)(m0 + srow) * lda;
    // B staging geometry (pre-swizzled global source)
    int brow8 = lane >> 3;
    int bc16 = (lane & 7) ^ brow8;
    bool aff = (scH != nullptr);

    if (aff) {
        for (int i = tid; i < lda; i += 512) {
            scS[i] = scH[i];
            shS[i] = shH[i];
        }
    }
    __syncthreads();

    // ---- prologue: full stage(0) + A(1) reg prefetch ----
    uint4v vA0 = *(const uint4v*)(aRow + sc16 * 8);
    uint4v vA1 = *(const uint4v*)(aRow + (sc16 + 4) * 8);
    {
        uint4v w0 = vA0, w1 = vA1;
        if (aff) {
            f16x8 a0 = *(f16x8*)&w0, a1 = *(f16x8*)&w1;
            f16x8 s0 = *(const f16x8*)&scS[sc16 * 8];
            f16x8 h0 = *(const f16x8*)&shS[sc16 * 8];
            f16x8 s1 = *(const f16x8*)&scS[(sc16 + 4) * 8];
            f16x8 h1 = *(const f16x8*)&shS[(sc16 + 4) * 8];
#pragma unroll
            for (int i = 0; i < 8; i++) {
                _Float16 t0 = a0[i] * s0[i] + h0[i];
                _Float16 t1 = a1[i] * s1[i] + h1[i];
                a0[i] = t0 > (_Float16)0 ? t0 : (_Float16)0;
                a1[i] = t1 > (_Float16)0 ? t1 : (_Float16)0;
            }
            w0 = *(uint4v*)&a0;
            w1 = *(uint4v*)&a1;
        }
        unsigned short* As = smem;
        *(uint4v*)&As[srow * 64 + ((sc16 ^ swz) * 8)] = w0;
        *(uint4v*)&As[srow * 64 + (((sc16 + 4) ^ swz) * 8)] = w1;
        unsigned short* Bs = smem + 16384;
#pragma unroll
        for (int j = 0; j < 5; ++j) {
            int chunk = wid * 5 + j;
            int n = chunk * 8 + brow8;
            const unsigned short* g = Bb + (size_t)n * lda + bc16 * 8;
            __builtin_amdgcn_global_load_lds(
                (const __attribute__((address_space(1))) unsigned int*)g,
                (__attribute__((address_space(3))) unsigned int*)&Bs[chunk * 512], 16, 0, 0);
        }
    }
    __builtin_amdgcn_sched_barrier(0);
    if (kIters > 1) {
        vA0 = *(const uint4v*)(aRow + 64 + sc16 * 8);
        vA1 = *(const uint4v*)(aRow + 64 + (sc16 + 4) * 8);
        asm volatile("s_waitcnt vmcnt(2) lgkmcnt(0)" ::: "memory");
    } else {
        asm volatile("s_waitcnt vmcnt(0) lgkmcnt(0)" ::: "memory");
    }
    __builtin_amdgcn_s_barrier();

    f32x4 acc[4][5] = {};
    for (int kt = 0; kt < kIters; ++kt) {
        unsigned short* As = smem + (kt & 1) * 8192;
        unsigned short* Bs = smem + 16384 + (kt & 1) * 20480;
        // ---- stage(kt+1) into the other buffers (issued before compute) ----
        if (kt + 1 < kIters) {
            int k1 = (kt + 1) * 64;
            unsigned short* As2 = smem + ((kt + 1) & 1) * 8192;
            unsigned short* Bs2 = smem + 16384 + ((kt + 1) & 1) * 20480;
            uint4v w0 = vA0, w1 = vA1;   // A(kt+1), prefetched last iter
            if (aff) {
                f16x8 a0 = *(f16x8*)&w0, a1 = *(f16x8*)&w1;
                f16x8 s0 = *(const f16x8*)&scS[k1 + sc16 * 8];
                f16x8 h0 = *(const f16x8*)&shS[k1 + sc16 * 8];
                f16x8 s1 = *(const f16x8*)&scS[k1 + (sc16 + 4) * 8];
                f16x8 h1 = *(const f16x8*)&shS[k1 + (sc16 + 4) * 8];
#pragma unroll
                for (int i = 0; i < 8; i++) {
                    _Float16 t0 = a0[i] * s0[i] + h0[i];
                    _Float16 t1 = a1[i] * s1[i] + h1[i];
                    a0[i] = t0 > (_Float16)0 ? t0 : (_Float16)0;
                    a1[i] = t1 > (_Float16)0 ? t1 : (_Float16)0;
                }
                w0 = *(uint4v*)&a0;
                w1 = *(uint4v*)&a1;
            }
            *(uint4v*)&As2[srow * 64 + ((sc16 ^ swz) * 8)] = w0;
            *(uint4v*)&As2[srow * 64 + (((sc16 + 4) ^ swz) * 8)] = w1;
#pragma unroll
            for (int j = 0; j < 5; ++j) {
                int chunk = wid * 5 + j;
                int n = chunk * 8 + brow8;
                const unsigned short* g = Bb + (size_t)n * lda + k1 + bc16 * 8;
                __builtin_amdgcn_global_load_lds(
                    (const __attribute__((address_space(1))) unsigned int*)g,
                    (__attribute__((address_space(3))) unsigned int*)&Bs2[chunk * 512], 16, 0, 0);
            }
            __builtin_amdgcn_sched_barrier(0);  // keep A(kt+2) loads newest in vmcnt order
            if (kt + 2 < kIters) {
                int k2 = (kt + 2) * 64;
                vA0 = *(const uint4v*)(aRow + k2 + sc16 * 8);
                vA1 = *(const uint4v*)(aRow + k2 + (sc16 + 4) * 8);
            }
        }
        // ---- compute(kt) from As/Bs (compiler-scheduled) ----
#pragma unroll
        for (int ks = 0; ks < 2; ++ks) {
            f16x8 af[4];
#pragma unroll
            for (int mf = 0; mf < 4; ++mf) {
                int ra = wm * 64 + mf * 16 + (lane & 15);
                int c16 = (ks * 4 + (lane >> 4)) ^ (ra & 7);
                af[mf] = *(const f16x8*)&As[ra * 64 + c16 * 8];
            }
#pragma unroll
            for (int nf = 0; nf < 5; ++nf) {
                int rb = wn * 80 + nf * 16 + (lane & 15);
                int c16 = (ks * 4 + (lane >> 4)) ^ (rb & 7);
                f16x8 bg = *(const f16x8*)&Bs[rb * 64 + c16 * 8];
                // swapped operands -> acc holds D^T (lane&15=m, (lane>>4)*4+i=n)
#pragma unroll
                for (int mf = 0; mf < 4; ++mf)
                    acc[mf][nf] = __builtin_amdgcn_mfma_f32_16x16x32_f16(bg, af[mf], acc[mf][nf], 0, 0, 0);
            }
        }
        // ---- counted drain + single barrier ----
        if (kt + 1 < kIters) {
            if (kt + 2 < kIters) {
                asm volatile("s_waitcnt vmcnt(2) lgkmcnt(0)" ::: "memory");
            } else {
                asm volatile("s_waitcnt vmcnt(0) lgkmcnt(0)" ::: "memory");
            }
            __builtin_amdgcn_s_barrier();
        }
    }

    // ---- per-column stats (f16-rounded, matching stored C) ----
#pragma unroll
    for (int nf = 0; nf < 5; ++nf) {
        float s[4] = {0, 0, 0, 0}, ss[4] = {0, 0, 0, 0};
#pragma unroll
        for (int mf = 0; mf < 4; ++mf) {
#pragma unroll
            for (int i = 0; i < 4; ++i) {
                float vr = h2f(f2h(acc[mf][nf][i]));
                s[i] += vr;
                ss[i] += vr * vr;
            }
        }
#pragma unroll
        for (int off = 1; off < 16; off <<= 1) {
#pragma unroll
            for (int i = 0; i < 4; ++i) {
                s[i] += __shfl_xor(s[i], off);
                ss[i] += __shfl_xor(ss[i], off);
            }
        }
        if ((lane & 15) == 0) {
            int cb = n0 + wn * 80 + nf * 16 + ((lane >> 4) << 2);
#pragma unroll
            for (int i = 0; i < 4; ++i) {
                atomicAdd(&stats[cb + i], s[i]);
                atomicAdd(&stats[statN + cb + i], ss[i]);
            }
        }
    }

    // ---- LDS-transpose epilogue: b64 writes, coalesced dwordx4 row stores ----
    unsigned short* T = smem;  // 64 x TLD f16 = 41 KB
#pragma unroll
    for (int half = 0; half < 2; ++half) {
        __syncthreads();
        if (wm == half) {
#pragma unroll
            for (int nf = 0; nf < 5; ++nf) {
#pragma unroll
                for (int mf = 0; mf < 4; ++mf) {
                    int r = mf * 16 + (lane & 15);
                    int cb = wn * 80 + nf * 16 + ((lane >> 4) << 2);
                    s16x4 w;
#pragma unroll
                    for (int i = 0; i < 4; ++i) w[i] = (short)f2h(acc[mf][nf][i]);
                    *(s16x4*)&T[r * TLD + cb] = w;
                }
            }
        }
        __syncthreads();
        int rowbase = m0 + half * 64;
#pragma unroll
        for (int p = 0; p < 5; ++p) {
            int cid = p * 512 + tid;          // 0..2559
            int r = cid / 40, c16 = cid % 40;
            uint4v v = *(const uint4v*)&T[r * TLD + c16 * 8];
            *(uint4v*)&C[(size_t)(rowbase + r) * ldc + n0 + c16 * 8] = v;
        }
    }
}

// ---------------- BN scale/shift from stats (f32 + f16 copies) ----------------
__global__ void k_bnprep(const float* __restrict__ stats, int statN, int realN,
                         const float* __restrict__ g, const float* __restrict__ b,
                         float* __restrict__ sc, float* __restrict__ sh,
                         unsigned short* __restrict__ scH, unsigned short* __restrict__ shH) {
    int n = blockIdx.x * 256 + threadIdx.x;
    if (n >= statN) return;
    float scv = 0.f, shv = 0.f;
    if (n < realN) {
        float mu = stats[n] * (1.f / NN);
        float var = stats[statN + n] * (1.f / NN) - mu * mu;
        var = fmaxf(var, 0.f);
        float rs = rsqrtf(var + BN_EPS);
        scv = g[n] * rs;
        shv = b[n] - mu * scv;
    }
    sc[n] = scv;
    sh[n] = shv;
    scH[n] = f2h(scv);
    shH[n] = f2h(shv);
}

// ---------------- final output ----------------
__global__ void k_out(const unsigned short* __restrict__ u2, const float* __restrict__ sc,
                      const float* __restrict__ sh, float* __restrict__ out) {
    unsigned int idx = blockIdx.x * 256u + threadIdx.x;
    if (idx >= (unsigned int)NN * DD) return;
    unsigned int n = idx / DD, d = idx % DD;
    out[idx] = sc[d] * h2f(u2[(size_t)n * DP + d]) + sh[d];
}

extern "C" void kernel_launch(void* const* d_in, const int* in_sizes, int n_in,
                              void* d_out, int out_size, void* d_ws, size_t ws_size,
                              hipStream_t stream) {
    const int* x = (const int*)d_in[0];
    const int* ei = (const int*)d_in[1];
    const int* ea = (const int*)d_in[2];
    const float* xe1 = (const float*)d_in[3];
    const float* xe2 = (const float*)d_in[4];
    const float* ee1 = (const float*)d_in[5];
    const float* ee2 = (const float*)d_in[6];
    const float* W1 = (const float*)d_in[7];
    const float* bn1g = (const float*)d_in[9];
    const float* bn1b = (const float*)d_in[10];
    const float* W2 = (const float*)d_in[11];
    const float* bng = (const float*)d_in[13];
    const float* bnb = (const float*)d_in[14];
    float* out = (float*)d_out;

    const int smemBytes = SMEM_SHORTS * 2;  // 117248
    hipFuncSetAttribute((const void*)k_gemmN, hipFuncAttributeMaxDynamicSharedMemorySize,
                        smemBytes);

    char* ws = (char*)d_ws;
    size_t off = 0;
    auto alloc = [&](size_t bytes) -> void* {
        void* p = ws + off;
        off += (bytes + 255) & ~(size_t)255;
        return p;
    };
    unsigned short* hbuf = (unsigned short*)alloc((size_t)NN * DP * 2);   // h0 / u2
    unsigned short* agg  = (unsigned short*)alloc((size_t)NN * DP * 2);
    unsigned short* u1   = (unsigned short*)alloc((size_t)NN * D2P * 2);
    unsigned short* W1t  = (unsigned short*)alloc((size_t)NL * D2P * DP * 2);
    unsigned short* W2t  = (unsigned short*)alloc((size_t)NL * DP * D2P * 2);
    unsigned short* eec  = (unsigned short*)alloc((size_t)NL * 15 * DP * 2);
    int* row_ptr = (int*)alloc((size_t)(NN + 1) * 4);
    int* cursor  = (int*)alloc((size_t)NN * 4);
    int* counts  = (int*)alloc((size_t)NN * 4);
    int* srcs    = (int*)alloc((size_t)NE * 4);
    int* combos  = (int*)alloc((size_t)NE * 4);
    int* partial  = (int*)alloc(512 * 4);
    int* partial2 = (int*)alloc(512 * 4);
    float* stats1 = (float*)alloc(2 * D2P * 4);
    float* stats2 = (float*)alloc(2 * DP * 4);
    float* sc1 = (float*)alloc(D2P * 4);
    float* sh1 = (float*)alloc(D2P * 4);
    float* sc2 = (float*)alloc(DP * 4);
    float* sh2 = (float*)alloc(DP * 4);
    float* sc0 = (float*)alloc(DP * 4);
    float* sh0 = (float*)alloc(DP * 4);
    unsigned short* scH1 = (unsigned short*)alloc(D2P * 2);
    unsigned short* shH1 = (unsigned short*)alloc(D2P * 2);
    unsigned short* scH2 = (unsigned short*)alloc(DP * 2);
    unsigned short* shH2 = (unsigned short*)alloc(DP * 2);

    // prep
    k_w1t<<<NL * D2P * DP / 256, 256, 0, stream>>>(W1, W1t);
    k_w2t<<<NL * DP * D2P / 256, 256, 0, stream>>>(W2, W2t);
    k_eec<<<(NL * 15 * DP + 255) / 256, 256, 0, stream>>>(ee1, ee2, eec);
    k_h0<<<NN * DP / 256, 256, 0, stream>>>(x, xe1, xe2, hbuf);
    k_ident<<<2, 256, 0, stream>>>(sc0, sh0);

    // CSR
    hipMemsetAsync(counts, 0, (size_t)NN * 4, stream);
    k_count<<<NE / 256, 256, 0, stream>>>(ei, counts);
    k_scan1<<<NN / 256, 256, 0, stream>>>(counts, partial);
    k_scan2<<<1, 512, 0, stream>>>(partial, partial2);
    k_scan3<<<NN / 256, 256, 0, stream>>>(counts, partial2, row_ptr, cursor);
    k_fill<<<NE / 256, 256, 0, stream>>>(ei, ea, cursor, srcs, combos);

    const unsigned short* hcur = hbuf;
    const float* scIn = sc0;
    const float* shIn = sh0;
    int reluIn = 0;
    for (int l = 0; l < NL; ++l) {
        k_gather<<<NN * 40 / 256, 256, 0, stream>>>(hcur, scIn, shIn, reluIn, row_ptr, srcs,
                                                    combos, eec + (size_t)l * 15 * DP, agg);
        hipMemsetAsync(stats1, 0, 2 * D2P * 4, stream);
        dim3 g1(D2P / 320, NN / 128);
        k_gemmN<<<g1, 512, smemBytes, stream>>>(agg, DP, DP / 64, nullptr, nullptr,
                                                W1t + (size_t)l * D2P * DP, u1, D2P, stats1, D2P);
        k_bnprep<<<(D2P + 255) / 256, 256, 0, stream>>>(stats1, D2P, D2, bn1g + (size_t)l * D2,
                                                        bn1b + (size_t)l * D2, sc1, sh1, scH1, shH1);
        hipMemsetAsync(stats2, 0, 2 * DP * 4, stream);
        dim3 g2(DP / 320, NN / 128);
        k_gemmN<<<g2, 512, smemBytes, stream>>>(u1, D2P, D2P / 64, scH1, shH1,
                                                W2t + (size_t)l * DP * D2P, hbuf, DP, stats2, DP);
        k_bnprep<<<(DP + 255) / 256, 256, 0, stream>>>(stats2, DP, DD, bng + (size_t)l * DD,
                                                       bnb + (size_t)l * DD, sc2, sh2, scH2, shH2);
        hcur = hbuf;
        scIn = sc2;
        shIn = sh2;
        reluIn = 1;
    }
    k_out<<<(unsigned int)NN * DD / 256, 256, 0, stream>>>(hbuf, sc2, sh2, out);
}

// Round 11
// 3278.797 us; speedup vs baseline: 1.5468x; 1.0108x over previous
//
#include <hip/hip_runtime.h>
#include <hip/hip_bf16.h>
#include <stdint.h>

#define NN 131072
#define NE 262144
#define DD 300
#define DP 320
#define D2 600
#define D2P 640
#define NL 5
#define BN_EPS 1e-5f

typedef __attribute__((ext_vector_type(8))) _Float16 f16x8;
typedef __attribute__((ext_vector_type(4))) float f32x4;
typedef __attribute__((ext_vector_type(4))) unsigned int uint4v;
typedef __attribute__((ext_vector_type(4))) short s16x4;

static __device__ __forceinline__ float h2f(unsigned short u) {
    union { unsigned short u; _Float16 h; } c; c.u = u; return (float)c.h;
}
static __device__ __forceinline__ unsigned short f2h(float f) {
    union { unsigned short u; _Float16 h; } c; c.h = (_Float16)f; return c.u;
}

// ---------------- prep kernels ----------------

__global__ void k_w1t(const float* __restrict__ W1, unsigned short* __restrict__ W1t) {
    int idx = blockIdx.x * 256 + threadIdx.x;
    if (idx >= NL * D2P * DP) return;
    int l = idx / (D2P * DP);
    int r = idx % (D2P * DP);
    int n = r / DP, k = r % DP;
    float v = (n < D2 && k < DD) ? W1[(size_t)(l * DD + k) * D2 + n] : 0.f;
    W1t[idx] = f2h(v);
}

__global__ void k_w2t(const float* __restrict__ W2, unsigned short* __restrict__ W2t) {
    int idx = blockIdx.x * 256 + threadIdx.x;
    if (idx >= NL * DP * D2P) return;
    int l = idx / (DP * D2P);
    int r = idx % (DP * D2P);
    int n = r / D2P, k = r % D2P;
    float v = (n < DD && k < D2) ? W2[(size_t)(l * D2 + k) * DD + n] : 0.f;
    W2t[idx] = f2h(v);
}

__global__ void k_eec(const float* __restrict__ ee1, const float* __restrict__ ee2,
                      unsigned short* __restrict__ eec) {
    int idx = blockIdx.x * 256 + threadIdx.x;
    if (idx >= NL * 15 * DP) return;
    int l = idx / (15 * DP);
    int r = idx % (15 * DP);
    int cb = r / DP, c = r % DP;
    int b = cb / 3, d = cb % 3;
    float v = 0.f;
    if (c < DD) v = ee1[(size_t)(l * 5 + b) * DD + c] + ee2[(size_t)(l * 3 + d) * DD + c];
    eec[idx] = f2h(v);
}

__global__ void k_h0(const int* __restrict__ x, const float* __restrict__ xe1,
                     const float* __restrict__ xe2, unsigned short* __restrict__ h) {
    unsigned int idx = blockIdx.x * 256u + threadIdx.x;
    if (idx >= (unsigned int)NN * DP) return;
    unsigned int n = idx / DP, c = idx % DP;
    float v = 0.f;
    if (c < DD) v = xe1[(size_t)x[2 * n] * DD + c] + xe2[(size_t)x[2 * n + 1] * DD + c];
    h[idx] = f2h(v);
}

__global__ void k_ident(float* __restrict__ sc, float* __restrict__ sh) {
    int t = blockIdx.x * 256 + threadIdx.x;
    if (t < DP) { sc[t] = 1.f; sh[t] = 0.f; }
}

// ---------------- CSR build ----------------

__global__ void k_count(const int* __restrict__ ei, int* __restrict__ counts) {
    int e = blockIdx.x * 256 + threadIdx.x;
    if (e < NE) atomicAdd(&counts[ei[NE + e]], 1);
}

__global__ void k_scan1(const int* __restrict__ counts, int* __restrict__ partial) {
    __shared__ int sm[256];
    int t = threadIdx.x;
    sm[t] = counts[blockIdx.x * 256 + t];
    __syncthreads();
    for (int o = 128; o > 0; o >>= 1) {
        if (t < o) sm[t] += sm[t + o];
        __syncthreads();
    }
    if (t == 0) partial[blockIdx.x] = sm[0];
}

__global__ void k_scan2(const int* __restrict__ partial, int* __restrict__ partial2) {
    __shared__ int sm[512];
    int t = threadIdx.x;
    int v = partial[t];
    sm[t] = v;
    __syncthreads();
    for (int o = 1; o < 512; o <<= 1) {
        int add = (t >= o) ? sm[t - o] : 0;
        __syncthreads();
        sm[t] += add;
        __syncthreads();
    }
    partial2[t] = sm[t] - v;  // exclusive
}

__global__ void k_scan3(const int* __restrict__ counts, const int* __restrict__ partial2,
                        int* __restrict__ row_ptr, int* __restrict__ cursor) {
    __shared__ int sm[256];
    int t = threadIdx.x;
    int i = blockIdx.x * 256 + t;
    int v = counts[i];
    sm[t] = v;
    __syncthreads();
    for (int o = 1; o < 256; o <<= 1) {
        int add = (t >= o) ? sm[t - o] : 0;
        __syncthreads();
        sm[t] += add;
        __syncthreads();
    }
    int excl = partial2[blockIdx.x] + sm[t] - v;
    row_ptr[i] = excl;
    cursor[i] = excl;
    if (i == NN - 1) row_ptr[NN] = excl + v;
}

__global__ void k_fill(const int* __restrict__ ei, const int* __restrict__ ea,
                       int* __restrict__ cursor, int* __restrict__ srcs,
                       int* __restrict__ combos) {
    int e = blockIdx.x * 256 + threadIdx.x;
    if (e >= NE) return;
    int d = ei[NE + e];
    int pos = atomicAdd(&cursor[d], 1);
    srcs[pos] = ei[e];
    combos[pos] = ea[2 * e] * 3 + ea[2 * e + 1];
}

// ---------------- aggregation (pull, CSR) ----------------
__global__ void k_gather(const unsigned short* __restrict__ h, const float* __restrict__ sc,
                         const float* __restrict__ sh, int relu,
                         const int* __restrict__ row_ptr, const int* __restrict__ srcs,
                         const int* __restrict__ combos, const unsigned short* __restrict__ eec,
                         unsigned short* __restrict__ agg) {
    unsigned int idx = blockIdx.x * 256u + threadIdx.x;  // N*40 chunks of 8 cols
    if (idx >= (unsigned int)NN * 40) return;
    unsigned int m = idx / 40;
    unsigned int j = idx % 40;
    int c0 = j * 8;
    float a[8] = {0, 0, 0, 0, 0, 0, 0, 0};
    float scv[8], shv[8];
#pragma unroll
    for (int i = 0; i < 8; i++) { scv[i] = sc[c0 + i]; shv[i] = sh[c0 + i]; }
    int e0 = row_ptr[m], e1 = row_ptr[m + 1];
    for (int e = e0; e < e1; ++e) {
        int s = srcs[e], cb = combos[e];
        uint4v hv = *(const uint4v*)(h + (size_t)s * DP + c0);
        uint4v ev = *(const uint4v*)(eec + (size_t)cb * DP + c0);
        const unsigned short* hp = (const unsigned short*)&hv;
        const unsigned short* ep = (const unsigned short*)&ev;
#pragma unroll
        for (int i = 0; i < 8; i++) {
            float f = scv[i] * h2f(hp[i]) + shv[i];
            if (relu) f = fmaxf(f, 0.f);
            a[i] += f + h2f(ep[i]);
        }
    }
    unsigned short o[8];
#pragma unroll
    for (int i = 0; i < 8; i++) o[i] = f2h(a[i]);
    *(uint4v*)(agg + (size_t)m * DP + c0) = *(const uint4v*)o;
}

// ---------------- big-N GEMM (round-4 structure; AFF=0 uses DMA for A too) ----------------
// C[M, n0..n0+319] = affine?(A)[M,K] @ B^T, grid (Nout/320, M/128), 512 thr, 8 waves (2m x 4n).
// AFF=0: A staged via global_load_lds with pre-swizzled global source (same geometry as B).
// AFF=1: A reg-staged with f16 affine+relu fold (byte-identical to the 1839-us round-4 path).
// Epilogue: per-column stats + LDS-transpose + coalesced dwordx4 row stores.
#define TLD 328
template<int AFF>
__launch_bounds__(512, 2)
__global__ void k_gemmN(const unsigned short* __restrict__ A, int lda, int kIters,
                        const unsigned short* __restrict__ scH,
                        const unsigned short* __restrict__ shH,
                        const unsigned short* __restrict__ B,
                        unsigned short* __restrict__ C, int ldc,
                        float* __restrict__ stats, int statN) {
    __shared__ unsigned short smem[128 * 64 + 320 * 64];  // As | Bs ; reused as T[64][TLD]
    unsigned short* As = smem;
    unsigned short* Bs = smem + 128 * 64;
    int tid = threadIdx.x;
    int lane = tid & 63, wid = tid >> 6;
    int wm = wid >> 2, wn = wid & 3;
    int m0 = blockIdx.y * 128;
    int n0 = blockIdx.x * 320;
    const unsigned short* Bb = B + (size_t)n0 * lda;

    // reg-staged A geometry (AFF=1): thread -> (row, two 16B slots)
    int srow = tid >> 2;       // 0..127
    int sc16 = tid & 3;        // slots sc16 and sc16+4
    int swz = srow & 7;
    const unsigned short* aRow = A + (size_t)(m0 + srow) * lda;
    // DMA staging geometry (B always; A when AFF=0): 8-row chunks, pre-swizzled slot
    int brow8 = lane >> 3;          // row within 8-row chunk
    int bc16 = (lane & 7) ^ brow8;  // pre-swizzled global slot ((l&7)^(row&7), row%8==l>>3)
    const unsigned short* Ab = A + (size_t)m0 * lda;

    f32x4 acc[4][5] = {};

    for (int kt = 0; kt < kIters; ++kt) {
        int k0 = kt * 64;
        // B DMA: 5 chunks per wave (40 chunks = 320 rows x 64 cols)
#pragma unroll
        for (int j = 0; j < 5; ++j) {
            int chunk = wid * 5 + j;
            int n = chunk * 8 + brow8;
            const unsigned short* g = Bb + (size_t)n * lda + k0 + bc16 * 8;
            __builtin_amdgcn_global_load_lds(
                (const __attribute__((address_space(1))) unsigned int*)g,
                (__attribute__((address_space(3))) unsigned int*)&Bs[chunk * 512], 16, 0, 0);
        }
        if (AFF == 0) {
            // A DMA: 2 chunks per wave (16 chunks = 128 rows x 64 cols), pre-swizzled src
#pragma unroll
            for (int j = 0; j < 2; ++j) {
                int chunk = wid * 2 + j;
                int row = chunk * 8 + brow8;
                const unsigned short* g = Ab + (size_t)row * lda + k0 + bc16 * 8;
                __builtin_amdgcn_global_load_lds(
                    (const __attribute__((address_space(1))) unsigned int*)g,
                    (__attribute__((address_space(3))) unsigned int*)&As[chunk * 512], 16, 0, 0);
            }
        } else {
            // A: global -> reg -> f16 affine+relu -> swizzled LDS (round-4 path)
            uint4v v0 = *(const uint4v*)(aRow + k0 + sc16 * 8);
            uint4v v1 = *(const uint4v*)(aRow + k0 + (sc16 + 4) * 8);
            f16x8 a0 = *(f16x8*)&v0, a1 = *(f16x8*)&v1;
            f16x8 s0 = *(const f16x8*)&scH[k0 + sc16 * 8];
            f16x8 h0 = *(const f16x8*)&shH[k0 + sc16 * 8];
            f16x8 s1 = *(const f16x8*)&scH[k0 + (sc16 + 4) * 8];
            f16x8 h1 = *(const f16x8*)&shH[k0 + (sc16 + 4) * 8];
#pragma unroll
            for (int i = 0; i < 8; i++) {
                _Float16 t0 = a0[i] * s0[i] + h0[i];
                _Float16 t1 = a1[i] * s1[i] + h1[i];
                a0[i] = t0 > (_Float16)0 ? t0 : (_Float16)0;
                a1[i] = t1 > (_Float16)0 ? t1 : (_Float16)0;
            }
            v0 = *(uint4v*)&a0;
            v1 = *(uint4v*)&a1;
            *(uint4v*)&As[srow * 64 + ((sc16 ^ swz) * 8)] = v0;
            *(uint4v*)&As[srow * 64 + (((sc16 + 4) ^ swz) * 8)] = v1;
        }
        __syncthreads();
#pragma unroll
        for (int ks = 0; ks < 2; ++ks) {
            f16x8 af[4];
#pragma unroll
            for (int mf = 0; mf < 4; ++mf) {
                int ra = wm * 64 + mf * 16 + (lane & 15);
                int c16 = (ks * 4 + (lane >> 4)) ^ (ra & 7);
                af[mf] = *(const f16x8*)&As[ra * 64 + c16 * 8];
            }
#pragma unroll
            for (int nf = 0; nf < 5; ++nf) {
                int rb = wn * 80 + nf * 16 + (lane & 15);
                int c16 = (ks * 4 + (lane >> 4)) ^ (rb & 7);
                f16x8 bg = *(const f16x8*)&Bs[rb * 64 + c16 * 8];
                // swapped operands -> acc holds D^T (lane&15=m, (lane>>4)*4+i=n)
#pragma unroll
                for (int mf = 0; mf < 4; ++mf)
                    acc[mf][nf] = __builtin_amdgcn_mfma_f32_16x16x32_f16(bg, af[mf], acc[mf][nf], 0, 0, 0);
            }
        }
        __syncthreads();
    }

    // ---- per-column stats (f16-rounded, matching stored C) ----
#pragma unroll
    for (int nf = 0; nf < 5; ++nf) {
        float s[4] = {0, 0, 0, 0}, ss[4] = {0, 0, 0, 0};
#pragma unroll
        for (int mf = 0; mf < 4; ++mf) {
#pragma unroll
            for (int i = 0; i < 4; ++i) {
                float vr = h2f(f2h(acc[mf][nf][i]));
                s[i] += vr;
                ss[i] += vr * vr;
            }
        }
#pragma unroll
        for (int off = 1; off < 16; off <<= 1) {
#pragma unroll
            for (int i = 0; i < 4; ++i) {
                s[i] += __shfl_xor(s[i], off);
                ss[i] += __shfl_xor(ss[i], off);
            }
        }
        if ((lane & 15) == 0) {
            int cb = n0 + wn * 80 + nf * 16 + ((lane >> 4) << 2);
#pragma unroll
            for (int i = 0; i < 4; ++i) {
                atomicAdd(&stats[cb + i], s[i]);
                atomicAdd(&stats[statN + cb + i], ss[i]);
            }
        }
    }

    // ---- LDS-transpose epilogue: b64 writes, coalesced dwordx4 row stores ----
    unsigned short* T = smem;  // 64 x TLD f16 = 41 KB
#pragma unroll
    for (int half = 0; half < 2; ++half) {
        __syncthreads();
        if (wm == half) {
#pragma unroll
            for (int nf = 0; nf < 5; ++nf) {
#pragma unroll
                for (int mf = 0; mf < 4; ++mf) {
                    int r = mf * 16 + (lane & 15);
                    int cb = wn * 80 + nf * 16 + ((lane >> 4) << 2);
                    s16x4 w;
#pragma unroll
                    for (int i = 0; i < 4; ++i) w[i] = (short)f2h(acc[mf][nf][i]);
                    *(s16x4*)&T[r * TLD + cb] = w;
                }
            }
        }
        __syncthreads();
        int rowbase = m0 + half * 64;
#pragma unroll
        for (int p = 0; p < 5; ++p) {
            int cid = p * 512 + tid;          // 0..2559
            int r = cid / 40, c16 = cid % 40;
            uint4v v = *(const uint4v*)&T[r * TLD + c16 * 8];
            *(uint4v*)&C[(size_t)(rowbase + r) * ldc + n0 + c16 * 8] = v;
        }
    }
}

// ---------------- BN scale/shift from stats (f32 + f16 copies) ----------------
__global__ void k_bnprep(const float* __restrict__ stats, int statN, int realN,
                         const float* __restrict__ g, const float* __restrict__ b,
                         float* __restrict__ sc, float* __restrict__ sh,
                         unsigned short* __restrict__ scH, unsigned short* __restrict__ shH) {
    int n = blockIdx.x * 256 + threadIdx.x;
    if (n >= statN) return;
    float scv = 0.f, shv = 0.f;
    if (n < realN) {
        float mu = stats[n] * (1.f / NN);
        float var = stats[statN + n] * (1.f / NN) - mu * mu;
        var = fmaxf(var, 0.f);
        float rs = rsqrtf(var + BN_EPS);
        scv = g[n] * rs;
        shv = b[n] - mu * scv;
    }
    sc[n] = scv;
    sh[n] = shv;
    scH[n] = f2h(scv);
    shH[n] = f2h(shv);
}

// ---------------- final output ----------------
__global__ void k_out(const unsigned short* __restrict__ u2, const float* __restrict__ sc,
                      const float* __restrict__ sh, float* __restrict__ out) {
    unsigned int idx = blockIdx.x * 256u + threadIdx.x;
    if (idx >= (unsigned int)NN * DD) return;
    unsigned int n = idx / DD, d = idx % DD;
    out[idx] = sc[d] * h2f(u2[(size_t)n * DP + d]) + sh[d];
}

extern "C" void kernel_launch(void* const* d_in, const int* in_sizes, int n_in,
                              void* d_out, int out_size, void* d_ws, size_t ws_size,
                              hipStream_t stream) {
    const int* x = (const int*)d_in[0];
    const int* ei = (const int*)d_in[1];
    const int* ea = (const int*)d_in[2];
    const float* xe1 = (const float*)d_in[3];
    const float* xe2 = (const float*)d_in[4];
    const float* ee1 = (const float*)d_in[5];
    const float* ee2 = (const float*)d_in[6];
    const float* W1 = (const float*)d_in[7];
    const float* bn1g = (const float*)d_in[9];
    const float* bn1b = (const float*)d_in[10];
    const float* W2 = (const float*)d_in[11];
    const float* bng = (const float*)d_in[13];
    const float* bnb = (const float*)d_in[14];
    float* out = (float*)d_out;

    char* ws = (char*)d_ws;
    size_t off = 0;
    auto alloc = [&](size_t bytes) -> void* {
        void* p = ws + off;
        off += (bytes + 255) & ~(size_t)255;
        return p;
    };
    unsigned short* hbuf = (unsigned short*)alloc((size_t)NN * DP * 2);   // h0 / u2
    unsigned short* agg  = (unsigned short*)alloc((size_t)NN * DP * 2);
    unsigned short* u1   = (unsigned short*)alloc((size_t)NN * D2P * 2);
    unsigned short* W1t  = (unsigned short*)alloc((size_t)NL * D2P * DP * 2);
    unsigned short* W2t  = (unsigned short*)alloc((size_t)NL * DP * D2P * 2);
    unsigned short* eec  = (unsigned short*)alloc((size_t)NL * 15 * DP * 2);
    int* row_ptr = (int*)alloc((size_t)(NN + 1) * 4);
    int* cursor  = (int*)alloc((size_t)NN * 4);
    int* counts  = (int*)alloc((size_t)NN * 4);
    int* srcs    = (int*)alloc((size_t)NE * 4);
    int* combos  = (int*)alloc((size_t)NE * 4);
    int* partial  = (int*)alloc(512 * 4);
    int* partial2 = (int*)alloc(512 * 4);
    float* stats1 = (float*)alloc(2 * D2P * 4);
    float* stats2 = (float*)alloc(2 * DP * 4);
    float* sc1 = (float*)alloc(D2P * 4);
    float* sh1 = (float*)alloc(D2P * 4);
    float* sc2 = (float*)alloc(DP * 4);
    float* sh2 = (float*)alloc(DP * 4);
    float* sc0 = (float*)alloc(DP * 4);
    float* sh0 = (float*)alloc(DP * 4);
    unsigned short* scH1 = (unsigned short*)alloc(D2P * 2);
    unsigned short* shH1 = (unsigned short*)alloc(D2P * 2);
    unsigned short* scH2 = (unsigned short*)alloc(DP * 2);
    unsigned short* shH2 = (unsigned short*)alloc(DP * 2);

    // prep
    k_w1t<<<NL * D2P * DP / 256, 256, 0, stream>>>(W1, W1t);
    k_w2t<<<NL * DP * D2P / 256, 256, 0, stream>>>(W2, W2t);
    k_eec<<<(NL * 15 * DP + 255) / 256, 256, 0, stream>>>(ee1, ee2, eec);
    k_h0<<<NN * DP / 256, 256, 0, stream>>>(x, xe1, xe2, hbuf);
    k_ident<<<2, 256, 0, stream>>>(sc0, sh0);

    // CSR
    hipMemsetAsync(counts, 0, (size_t)NN * 4, stream);
    k_count<<<NE / 256, 256, 0, stream>>>(ei, counts);
    k_scan1<<<NN / 256, 256, 0, stream>>>(counts, partial);
    k_scan2<<<1, 512, 0, stream>>>(partial, partial2);
    k_scan3<<<NN / 256, 256, 0, stream>>>(counts, partial2, row_ptr, cursor);
    k_fill<<<NE / 256, 256, 0, stream>>>(ei, ea, cursor, srcs, combos);

    const unsigned short* hcur = hbuf;
    const float* scIn = sc0;
    const float* shIn = sh0;
    int reluIn = 0;
    for (int l = 0; l < NL; ++l) {
        k_gather<<<NN * 40 / 256, 256, 0, stream>>>(hcur, scIn, shIn, reluIn, row_ptr, srcs,
                                                    combos, eec + (size_t)l * 15 * DP, agg);
        hipMemsetAsync(stats1, 0, 2 * D2P * 4, stream);
        dim3 g1(D2P / 320, NN / 128);
        k_gemmN<0><<<g1, 512, 0, stream>>>(agg, DP, DP / 64, nullptr, nullptr,
                                           W1t + (size_t)l * D2P * DP, u1, D2P, stats1, D2P);
        k_bnprep<<<(D2P + 255) / 256, 256, 0, stream>>>(stats1, D2P, D2, bn1g + (size_t)l * D2,
                                                        bn1b + (size_t)l * D2, sc1, sh1, scH1, shH1);
        hipMemsetAsync(stats2, 0, 2 * DP * 4, stream);
        dim3 g2(DP / 320, NN / 128);
        k_gemmN<1><<<g2, 512, 0, stream>>>(u1, D2P, D2P / 64, scH1, shH1,
                                           W2t + (size_t)l * DP * D2P, hbuf, DP, stats2, DP);
        k_bnprep<<<(DP + 255) / 256, 256, 0, stream>>>(stats2, DP, DD, bng + (size_t)l * DD,
                                                       bnb + (size_t)l * DD, sc2, sh2, scH2, shH2);
        hcur = hbuf;
        scIn = sc2;
        shIn = sh2;
        reluIn = 1;
    }
    k_out<<<(unsigned int)NN * DD / 256, 256, 0, stream>>>(hbuf, sc2, sh2, out);
}

// Round 13
// 1821.938 us; speedup vs baseline: 2.7836x; 1.7996x over previous
//
#include <hip/hip_runtime.h>
#include <hip/hip_bf16.h>
#include <stdint.h>

#define NN 131072
#define NE 262144
#define DD 300
#define DP 320
#define D2 600
#define D2P 640
#define NL 5
#define BN_EPS 1e-5f

typedef __attribute__((ext_vector_type(8))) _Float16 f16x8;
typedef __attribute__((ext_vector_type(4))) float f32x4;
typedef __attribute__((ext_vector_type(4))) unsigned int uint4v;

static __device__ __forceinline__ float h2f(unsigned short u) {
    union { unsigned short u; _Float16 h; } c; c.u = u; return (float)c.h;
}
static __device__ __forceinline__ unsigned short f2h(float f) {
    union { unsigned short u; _Float16 h; } c; c.h = (_Float16)f; return c.u;
}

// ---------------- prep kernels ----------------

__global__ void k_w1t(const float* __restrict__ W1, unsigned short* __restrict__ W1t) {
    int idx = blockIdx.x * 256 + threadIdx.x;
    if (idx >= NL * D2P * DP) return;
    int l = idx / (D2P * DP);
    int r = idx % (D2P * DP);
    int n = r / DP, k = r % DP;
    float v = (n < D2 && k < DD) ? W1[(size_t)(l * DD + k) * D2 + n] : 0.f;
    W1t[idx] = f2h(v);
}

__global__ void k_w2t(const float* __restrict__ W2, unsigned short* __restrict__ W2t) {
    int idx = blockIdx.x * 256 + threadIdx.x;
    if (idx >= NL * DP * D2P) return;
    int l = idx / (DP * D2P);
    int r = idx % (DP * D2P);
    int n = r / D2P, k = r % D2P;
    float v = (n < DD && k < D2) ? W2[(size_t)(l * D2 + k) * DD + n] : 0.f;
    W2t[idx] = f2h(v);
}

__global__ void k_eec(const float* __restrict__ ee1, const float* __restrict__ ee2,
                      unsigned short* __restrict__ eec) {
    int idx = blockIdx.x * 256 + threadIdx.x;
    if (idx >= NL * 15 * DP) return;
    int l = idx / (15 * DP);
    int r = idx % (15 * DP);
    int cb = r / DP, c = r % DP;
    int b = cb / 3, d = cb % 3;
    float v = 0.f;
    if (c < DD) v = ee1[(size_t)(l * 5 + b) * DD + c] + ee2[(size_t)(l * 3 + d) * DD + c];
    eec[idx] = f2h(v);
}

__global__ void k_h0(const int* __restrict__ x, const float* __restrict__ xe1,
                     const float* __restrict__ xe2, unsigned short* __restrict__ h) {
    unsigned int idx = blockIdx.x * 256u + threadIdx.x;
    if (idx >= (unsigned int)NN * DP) return;
    unsigned int n = idx / DP, c = idx % DP;
    float v = 0.f;
    if (c < DD) v = xe1[(size_t)x[2 * n] * DD + c] + xe2[(size_t)x[2 * n + 1] * DD + c];
    h[idx] = f2h(v);
}

__global__ void k_ident(float* __restrict__ sc, float* __restrict__ sh) {
    int t = blockIdx.x * 256 + threadIdx.x;
    if (t < DP) { sc[t] = 1.f; sh[t] = 0.f; }
}

// ---------------- CSR build ----------------

__global__ void k_count(const int* __restrict__ ei, int* __restrict__ counts) {
    int e = blockIdx.x * 256 + threadIdx.x;
    if (e < NE) atomicAdd(&counts[ei[NE + e]], 1);
}

__global__ void k_scan1(const int* __restrict__ counts, int* __restrict__ partial) {
    __shared__ int sm[256];
    int t = threadIdx.x;
    sm[t] = counts[blockIdx.x * 256 + t];
    __syncthreads();
    for (int o = 128; o > 0; o >>= 1) {
        if (t < o) sm[t] += sm[t + o];
        __syncthreads();
    }
    if (t == 0) partial[blockIdx.x] = sm[0];
}

__global__ void k_scan2(const int* __restrict__ partial, int* __restrict__ partial2) {
    __shared__ int sm[512];
    int t = threadIdx.x;
    int v = partial[t];
    sm[t] = v;
    __syncthreads();
    for (int o = 1; o < 512; o <<= 1) {
        int add = (t >= o) ? sm[t - o] : 0;
        __syncthreads();
        sm[t] += add;
        __syncthreads();
    }
    partial2[t] = sm[t] - v;  // exclusive
}

__global__ void k_scan3(const int* __restrict__ counts, const int* __restrict__ partial2,
                        int* __restrict__ row_ptr, int* __restrict__ cursor) {
    __shared__ int sm[256];
    int t = threadIdx.x;
    int i = blockIdx.x * 256 + t;
    int v = counts[i];
    sm[t] = v;
    __syncthreads();
    for (int o = 1; o < 256; o <<= 1) {
        int add = (t >= o) ? sm[t - o] : 0;
        __syncthreads();
        sm[t] += add;
        __syncthreads();
    }
    int excl = partial2[blockIdx.x] + sm[t] - v;
    row_ptr[i] = excl;
    cursor[i] = excl;
    if (i == NN - 1) row_ptr[NN] = excl + v;
}

__global__ void k_fill(const int* __restrict__ ei, const int* __restrict__ ea,
                       int* __restrict__ cursor, int* __restrict__ srcs,
                       int* __restrict__ combos) {
    int e = blockIdx.x * 256 + threadIdx.x;
    if (e >= NE) return;
    int d = ei[NE + e];
    int pos = atomicAdd(&cursor[d], 1);
    srcs[pos] = ei[e];
    combos[pos] = ea[2 * e] * 3 + ea[2 * e + 1];
}

// ---------------- aggregation (pull, CSR) ----------------
__global__ void k_gather(const unsigned short* __restrict__ h, const float* __restrict__ sc,
                         const float* __restrict__ sh, int relu,
                         const int* __restrict__ row_ptr, const int* __restrict__ srcs,
                         const int* __restrict__ combos, const unsigned short* __restrict__ eec,
                         unsigned short* __restrict__ agg) {
    unsigned int idx = blockIdx.x * 256u + threadIdx.x;  // N*40 chunks of 8 cols
    if (idx >= (unsigned int)NN * 40) return;
    unsigned int m = idx / 40;
    unsigned int j = idx % 40;
    int c0 = j * 8;
    float a[8] = {0, 0, 0, 0, 0, 0, 0, 0};
    float scv[8], shv[8];
#pragma unroll
    for (int i = 0; i < 8; i++) { scv[i] = sc[c0 + i]; shv[i] = sh[c0 + i]; }
    int e0 = row_ptr[m], e1 = row_ptr[m + 1];
    for (int e = e0; e < e1; ++e) {
        int s = srcs[e], cb = combos[e];
        uint4v hv = *(const uint4v*)(h + (size_t)s * DP + c0);
        uint4v ev = *(const uint4v*)(eec + (size_t)cb * DP + c0);
        const unsigned short* hp = (const unsigned short*)&hv;
        const unsigned short* ep = (const unsigned short*)&ev;
#pragma unroll
        for (int i = 0; i < 8; i++) {
            float f = scv[i] * h2f(hp[i]) + shv[i];
            if (relu) f = fmaxf(f, 0.f);
            a[i] += f + h2f(ep[i]);
        }
    }
    unsigned short o[8];
#pragma unroll
    for (int i = 0; i < 8; i++) o[i] = f2h(a[i]);
    *(uint4v*)(agg + (size_t)m * DP + c0) = *(const uint4v*)o;
}

// ---------------- k_gemm_r4: EXACT round-4 GEMM (measured 142 us/dispatch) ----------------
// C[M, n0..n0+319] = affine?(A)[M,K] @ B^T, grid (Nout/320, M/128), 512 thr, 8 waves (2m x 4n)
#define TLD 328
__launch_bounds__(512, 2)
__global__ void k_gemm_r4(const unsigned short* __restrict__ A, int lda, int kIters,
                          const unsigned short* __restrict__ scH,
                          const unsigned short* __restrict__ shH,
                          const unsigned short* __restrict__ B,
                          unsigned short* __restrict__ C, int ldc,
                          float* __restrict__ stats, int statN) {
    __shared__ unsigned short smem[128 * 64 + 320 * 64];  // As | Bs ; reused as T[64][TLD]
    unsigned short* As = smem;
    unsigned short* Bs = smem + 128 * 64;
    int tid = threadIdx.x;
    int lane = tid & 63, wid = tid >> 6;
    int wm = wid >> 2, wn = wid & 3;
    int m0 = blockIdx.y * 128;
    int n0 = blockIdx.x * 320;
    const unsigned short* Bb = B + (size_t)n0 * lda;

    // A staging geometry: thread -> (row, two 16B slots)
    int srow = tid >> 2;       // 0..127
    int sc16 = tid & 3;        // slots sc16 and sc16+4
    int swz = srow & 7;
    const unsigned short* aRow = A + (size_t)(m0 + srow) * lda;
    // B staging geometry
    int brow8 = lane >> 3;          // row within 8-row chunk
    int bc16 = (lane & 7) ^ brow8;  // pre-swizzled global slot

    f32x4 acc[4][5] = {};

    for (int kt = 0; kt < kIters; ++kt) {
        int k0 = kt * 64;
        // issue B DMA first (latency overlap)
#pragma unroll
        for (int j = 0; j < 5; ++j) {
            int chunk = wid * 5 + j;
            int n = chunk * 8 + brow8;
            const unsigned short* g = Bb + (size_t)n * lda + k0 + bc16 * 8;
            __builtin_amdgcn_global_load_lds(
                (const __attribute__((address_space(1))) unsigned int*)g,
                (__attribute__((address_space(3))) unsigned int*)&Bs[chunk * 512], 16, 0, 0);
        }
        // A: global -> reg -> (affine) -> swizzled LDS
        uint4v v0 = *(const uint4v*)(aRow + k0 + sc16 * 8);
        uint4v v1 = *(const uint4v*)(aRow + k0 + (sc16 + 4) * 8);
        if (scH) {
            f16x8 a0 = *(f16x8*)&v0, a1 = *(f16x8*)&v1;
            f16x8 s0 = *(const f16x8*)&scH[k0 + sc16 * 8];
            f16x8 h0 = *(const f16x8*)&shH[k0 + sc16 * 8];
            f16x8 s1 = *(const f16x8*)&scH[k0 + (sc16 + 4) * 8];
            f16x8 h1 = *(const f16x8*)&shH[k0 + (sc16 + 4) * 8];
#pragma unroll
            for (int i = 0; i < 8; i++) {
                _Float16 t0 = a0[i] * s0[i] + h0[i];
                _Float16 t1 = a1[i] * s1[i] + h1[i];
                a0[i] = t0 > (_Float16)0 ? t0 : (_Float16)0;
                a1[i] = t1 > (_Float16)0 ? t1 : (_Float16)0;
            }
            v0 = *(uint4v*)&a0;
            v1 = *(uint4v*)&a1;
        }
        *(uint4v*)&As[srow * 64 + ((sc16 ^ swz) * 8)] = v0;
        *(uint4v*)&As[srow * 64 + (((sc16 + 4) ^ swz) * 8)] = v1;
        __syncthreads();
#pragma unroll
        for (int ks = 0; ks < 2; ++ks) {
            f16x8 af[4];
#pragma unroll
            for (int mf = 0; mf < 4; ++mf) {
                int ra = wm * 64 + mf * 16 + (lane & 15);
                int c16 = (ks * 4 + (lane >> 4)) ^ (ra & 7);
                af[mf] = *(const f16x8*)&As[ra * 64 + c16 * 8];
            }
#pragma unroll
            for (int nf = 0; nf < 5; ++nf) {
                int rb = wn * 80 + nf * 16 + (lane & 15);
                int c16 = (ks * 4 + (lane >> 4)) ^ (rb & 7);
                f16x8 bg = *(const f16x8*)&Bs[rb * 64 + c16 * 8];
#pragma unroll
                for (int mf = 0; mf < 4; ++mf)
                    acc[mf][nf] = __builtin_amdgcn_mfma_f32_16x16x32_f16(af[mf], bg, acc[mf][nf], 0, 0, 0);
            }
        }
        __syncthreads();
    }

    // ---- per-column stats (on f16-rounded values, matching stored C) ----
#pragma unroll
    for (int nf = 0; nf < 5; ++nf) {
        int col = n0 + wn * 80 + nf * 16 + (lane & 15);
        float s = 0.f, ss = 0.f;
#pragma unroll
        for (int mf = 0; mf < 4; ++mf) {
#pragma unroll
            for (int i = 0; i < 4; ++i) {
                float vr = h2f(f2h(acc[mf][nf][i]));
                s += vr;
                ss += vr * vr;
            }
        }
        s += __shfl_xor(s, 16); s += __shfl_xor(s, 32);
        ss += __shfl_xor(ss, 16); ss += __shfl_xor(ss, 32);
        if (lane < 16) {
            atomicAdd(&stats[col], s);
            atomicAdd(&stats[statN + col], ss);
        }
    }

    // ---- LDS-transpose epilogue: coalesced row-major stores ----
    unsigned short* T = smem;  // 64 x TLD f16 = 41 KB, fits in As|Bs region
#pragma unroll
    for (int half = 0; half < 2; ++half) {
        __syncthreads();
        if (wm == half) {
#pragma unroll
            for (int nf = 0; nf < 5; ++nf) {
                int col = wn * 80 + nf * 16 + (lane & 15);
#pragma unroll
                for (int mf = 0; mf < 4; ++mf) {
                    int r = mf * 16 + ((lane >> 4) << 2);
#pragma unroll
                    for (int i = 0; i < 4; ++i)
                        T[(r + i) * TLD + col] = f2h(acc[mf][nf][i]);
                }
            }
        }
        __syncthreads();
        int rowbase = m0 + half * 64;
#pragma unroll
        for (int p = 0; p < 5; ++p) {
            int cid = p * 512 + tid;          // 0..2559
            int r = cid / 40, c16 = cid % 40;
            uint4v v = *(const uint4v*)&T[r * TLD + c16 * 8];
            *(uint4v*)&C[(size_t)(rowbase + r) * ldc + n0 + c16 * 8] = v;
        }
    }
}

// ---------------- k_gemm_dma: round-4 structure, A staged via global_load_lds ----------------
// No affine (GEMM1 only). A uses the same pre-swizzled-source DMA geometry as B:
// LDS[row][s] = A[row][s^(row&7)]; reader XORs (ra&7) back -> identical fragment values.
__launch_bounds__(512, 2)
__global__ void k_gemm_dma(const unsigned short* __restrict__ A, int lda, int kIters,
                           const unsigned short* __restrict__ B,
                           unsigned short* __restrict__ C, int ldc,
                           float* __restrict__ stats, int statN) {
    __shared__ unsigned short smem[128 * 64 + 320 * 64];
    unsigned short* As = smem;
    unsigned short* Bs = smem + 128 * 64;
    int tid = threadIdx.x;
    int lane = tid & 63, wid = tid >> 6;
    int wm = wid >> 2, wn = wid & 3;
    int m0 = blockIdx.y * 128;
    int n0 = blockIdx.x * 320;
    const unsigned short* Bb = B + (size_t)n0 * lda;
    const unsigned short* Ab = A + (size_t)m0 * lda;

    int brow8 = lane >> 3;
    int bc16 = (lane & 7) ^ brow8;

    f32x4 acc[4][5] = {};

    for (int kt = 0; kt < kIters; ++kt) {
        int k0 = kt * 64;
#pragma unroll
        for (int j = 0; j < 5; ++j) {
            int chunk = wid * 5 + j;
            int n = chunk * 8 + brow8;
            const unsigned short* g = Bb + (size_t)n * lda + k0 + bc16 * 8;
            __builtin_amdgcn_global_load_lds(
                (const __attribute__((address_space(1))) unsigned int*)g,
                (__attribute__((address_space(3))) unsigned int*)&Bs[chunk * 512], 16, 0, 0);
        }
#pragma unroll
        for (int j = 0; j < 2; ++j) {
            int chunk = wid * 2 + j;
            int row = chunk * 8 + brow8;
            const unsigned short* g = Ab + (size_t)row * lda + k0 + bc16 * 8;
            __builtin_amdgcn_global_load_lds(
                (const __attribute__((address_space(1))) unsigned int*)g,
                (__attribute__((address_space(3))) unsigned int*)&As[chunk * 512], 16, 0, 0);
        }
        __syncthreads();
#pragma unroll
        for (int ks = 0; ks < 2; ++ks) {
            f16x8 af[4];
#pragma unroll
            for (int mf = 0; mf < 4; ++mf) {
                int ra = wm * 64 + mf * 16 + (lane & 15);
                int c16 = (ks * 4 + (lane >> 4)) ^ (ra & 7);
                af[mf] = *(const f16x8*)&As[ra * 64 + c16 * 8];
            }
#pragma unroll
            for (int nf = 0; nf < 5; ++nf) {
                int rb = wn * 80 + nf * 16 + (lane & 15);
                int c16 = (ks * 4 + (lane >> 4)) ^ (rb & 7);
                f16x8 bg = *(const f16x8*)&Bs[rb * 64 + c16 * 8];
#pragma unroll
                for (int mf = 0; mf < 4; ++mf)
                    acc[mf][nf] = __builtin_amdgcn_mfma_f32_16x16x32_f16(af[mf], bg, acc[mf][nf], 0, 0, 0);
            }
        }
        __syncthreads();
    }

#pragma unroll
    for (int nf = 0; nf < 5; ++nf) {
        int col = n0 + wn * 80 + nf * 16 + (lane & 15);
        float s = 0.f, ss = 0.f;
#pragma unroll
        for (int mf = 0; mf < 4; ++mf) {
#pragma unroll
            for (int i = 0; i < 4; ++i) {
                float vr = h2f(f2h(acc[mf][nf][i]));
                s += vr;
                ss += vr * vr;
            }
        }
        s += __shfl_xor(s, 16); s += __shfl_xor(s, 32);
        ss += __shfl_xor(ss, 16); ss += __shfl_xor(ss, 32);
        if (lane < 16) {
            atomicAdd(&stats[col], s);
            atomicAdd(&stats[statN + col], ss);
        }
    }

    unsigned short* T = smem;
#pragma unroll
    for (int half = 0; half < 2; ++half) {
        __syncthreads();
        if (wm == half) {
#pragma unroll
            for (int nf = 0; nf < 5; ++nf) {
                int col = wn * 80 + nf * 16 + (lane & 15);
#pragma unroll
                for (int mf = 0; mf < 4; ++mf) {
                    int r = mf * 16 + ((lane >> 4) << 2);
#pragma unroll
                    for (int i = 0; i < 4; ++i)
                        T[(r + i) * TLD + col] = f2h(acc[mf][nf][i]);
                }
            }
        }
        __syncthreads();
        int rowbase = m0 + half * 64;
#pragma unroll
        for (int p = 0; p < 5; ++p) {
            int cid = p * 512 + tid;
            int r = cid / 40, c16 = cid % 40;
            uint4v v = *(const uint4v*)&T[r * TLD + c16 * 8];
            *(uint4v*)&C[(size_t)(rowbase + r) * ldc + n0 + c16 * 8] = v;
        }
    }
}

// ---------------- BN scale/shift from stats (f32 + f16 copies) ----------------
__global__ void k_bnprep(const float* __restrict__ stats, int statN, int realN,
                         const float* __restrict__ g, const float* __restrict__ b,
                         float* __restrict__ sc, float* __restrict__ sh,
                         unsigned short* __restrict__ scH, unsigned short* __restrict__ shH) {
    int n = blockIdx.x * 256 + threadIdx.x;
    if (n >= statN) return;
    float scv = 0.f, shv = 0.f;
    if (n < realN) {
        float mu = stats[n] * (1.f / NN);
        float var = stats[statN + n] * (1.f / NN) - mu * mu;
        var = fmaxf(var, 0.f);
        float rs = rsqrtf(var + BN_EPS);
        scv = g[n] * rs;
        shv = b[n] - mu * scv;
    }
    sc[n] = scv;
    sh[n] = shv;
    scH[n] = f2h(scv);
    shH[n] = f2h(shv);
}

// ---------------- final output ----------------
__global__ void k_out(const unsigned short* __restrict__ u2, const float* __restrict__ sc,
                      const float* __restrict__ sh, float* __restrict__ out) {
    unsigned int idx = blockIdx.x * 256u + threadIdx.x;
    if (idx >= (unsigned int)NN * DD) return;
    unsigned int n = idx / DD, d = idx % DD;
    out[idx] = sc[d] * h2f(u2[(size_t)n * DP + d]) + sh[d];
}

extern "C" void kernel_launch(void* const* d_in, const int* in_sizes, int n_in,
                              void* d_out, int out_size, void* d_ws, size_t ws_size,
                              hipStream_t stream) {
    const int* x = (const int*)d_in[0];
    const int* ei = (const int*)d_in[1];
    const int* ea = (const int*)d_in[2];
    const float* xe1 = (const float*)d_in[3];
    const float* xe2 = (const float*)d_in[4];
    const float* ee1 = (const float*)d_in[5];
    const float* ee2 = (const float*)d_in[6];
    const float* W1 = (const float*)d_in[7];
    const float* bn1g = (const float*)d_in[9];
    const float* bn1b = (const float*)d_in[10];
    const float* W2 = (const float*)d_in[11];
    const float* bng = (const float*)d_in[13];
    const float* bnb = (const float*)d_in[14];
    float* out = (float*)d_out;

    char* ws = (char*)d_ws;
    size_t off = 0;
    auto alloc = [&](size_t bytes) -> void* {
        void* p = ws + off;
        off += (bytes + 255) & ~(size_t)255;
        return p;
    };
    unsigned short* hbuf = (unsigned short*)alloc((size_t)NN * DP * 2);   // h0 / u2
    unsigned short* agg  = (unsigned short*)alloc((size_t)NN * DP * 2);
    unsigned short* u1   = (unsigned short*)alloc((size_t)NN * D2P * 2);
    unsigned short* W1t  = (unsigned short*)alloc((size_t)NL * D2P * DP * 2);
    unsigned short* W2t  = (unsigned short*)alloc((size_t)NL * DP * D2P * 2);
    unsigned short* eec  = (unsigned short*)alloc((size_t)NL * 15 * DP * 2);
    int* row_ptr = (int*)alloc((size_t)(NN + 1) * 4);
    int* cursor  = (int*)alloc((size_t)NN * 4);
    int* counts  = (int*)alloc((size_t)NN * 4);
    int* srcs    = (int*)alloc((size_t)NE * 4);
    int* combos  = (int*)alloc((size_t)NE * 4);
    int* partial  = (int*)alloc(512 * 4);
    int* partial2 = (int*)alloc(512 * 4);
    float* stats1 = (float*)alloc(2 * D2P * 4);
    float* stats2 = (float*)alloc(2 * DP * 4);
    float* sc1 = (float*)alloc(D2P * 4);
    float* sh1 = (float*)alloc(D2P * 4);
    float* sc2 = (float*)alloc(DP * 4);
    float* sh2 = (float*)alloc(DP * 4);
    float* sc0 = (float*)alloc(DP * 4);
    float* sh0 = (float*)alloc(DP * 4);
    unsigned short* scH1 = (unsigned short*)alloc(D2P * 2);
    unsigned short* shH1 = (unsigned short*)alloc(D2P * 2);
    unsigned short* scH2 = (unsigned short*)alloc(DP * 2);
    unsigned short* shH2 = (unsigned short*)alloc(DP * 2);

    // prep
    k_w1t<<<NL * D2P * DP / 256, 256, 0, stream>>>(W1, W1t);
    k_w2t<<<NL * DP * D2P / 256, 256, 0, stream>>>(W2, W2t);
    k_eec<<<(NL * 15 * DP + 255) / 256, 256, 0, stream>>>(ee1, ee2, eec);
    k_h0<<<NN * DP / 256, 256, 0, stream>>>(x, xe1, xe2, hbuf);
    k_ident<<<2, 256, 0, stream>>>(sc0, sh0);

    // CSR
    hipMemsetAsync(counts, 0, (size_t)NN * 4, stream);
    k_count<<<NE / 256, 256, 0, stream>>>(ei, counts);
    k_scan1<<<NN / 256, 256, 0, stream>>>(counts, partial);
    k_scan2<<<1, 512, 0, stream>>>(partial, partial2);
    k_scan3<<<NN / 256, 256, 0, stream>>>(counts, partial2, row_ptr, cursor);
    k_fill<<<NE / 256, 256, 0, stream>>>(ei, ea, cursor, srcs, combos);

    const unsigned short* hcur = hbuf;
    const float* scIn = sc0;
    const float* shIn = sh0;
    int reluIn = 0;
    for (int l = 0; l < NL; ++l) {
        k_gather<<<NN * 40 / 256, 256, 0, stream>>>(hcur, scIn, shIn, reluIn, row_ptr, srcs,
                                                    combos, eec + (size_t)l * 15 * DP, agg);
        hipMemsetAsync(stats1, 0, 2 * D2P * 4, stream);
        dim3 g1(D2P / 320, NN / 128);
        if (l & 1) {
            k_gemm_dma<<<g1, 512, 0, stream>>>(agg, DP, DP / 64,
                                               W1t + (size_t)l * D2P * DP, u1, D2P, stats1, D2P);
        } else {
            k_gemm_r4<<<g1, 512, 0, stream>>>(agg, DP, DP / 64, nullptr, nullptr,
                                              W1t + (size_t)l * D2P * DP, u1, D2P, stats1, D2P);
        }
        k_bnprep<<<(D2P + 255) / 256, 256, 0, stream>>>(stats1, D2P, D2, bn1g + (size_t)l * D2,
                                                        bn1b + (size_t)l * D2, sc1, sh1, scH1, shH1);
        hipMemsetAsync(stats2, 0, 2 * DP * 4, stream);
        dim3 g2(DP / 320, NN / 128);
        k_gemm_r4<<<g2, 512, 0, stream>>>(u1, D2P, D2P / 64, scH1, shH1,
                                          W2t + (size_t)l * DP * D2P, hbuf, DP, stats2, DP);
        k_bnprep<<<(DP + 255) / 256, 256, 0, stream>>>(stats2, DP, DD, bng + (size_t)l * DD,
                                                       bnb + (size_t)l * DD, sc2, sh2, scH2, shH2);
        hcur = hbuf;
        scIn = sc2;
        shIn = sh2;
        reluIn = 1;
    }
    k_out<<<(unsigned int)NN * DD / 256, 256, 0, stream>>>(hbuf, sc2, sh2, out);
}